// Round 1
// baseline (1050.008 us; speedup 1.0000x reference)
//
#include <hip/hip_runtime.h>
#include <hip/hip_bf16.h>
#include <stdint.h>

#define N_NODES 100000
#define N_EDGES 3200000
#define DDIM 256

static __device__ __forceinline__ unsigned short f32_to_bf16_rne(float f) {
  unsigned u = __float_as_uint(f);
  unsigned rounded = u + 0x7FFFu + ((u >> 16) & 1u);
  return (unsigned short)(rounded >> 16);
}

// ---------------- CSR build ----------------

__global__ void k_hist(const int* __restrict__ dst, int* __restrict__ deg) {
  int e = blockIdx.x * blockDim.x + threadIdx.x;
  if (e < N_EDGES) atomicAdd(&deg[dst[e]], 1);
}

__global__ __launch_bounds__(1024) void k_scan(const int* __restrict__ deg,
                                               int* __restrict__ rs,
                                               int* __restrict__ cur) {
  __shared__ int part[1024];
  int t = threadIdx.x;
  const int CH = (N_NODES + 1023) / 1024;  // 98
  int lo = t * CH;
  int hi = lo + CH;
  if (hi > N_NODES) hi = N_NODES;
  int s = 0;
  for (int i = lo; i < hi; ++i) s += deg[i];
  part[t] = s;
  __syncthreads();
  // inclusive Hillis-Steele scan
  for (int off = 1; off < 1024; off <<= 1) {
    int v = (t >= off) ? part[t - off] : 0;
    __syncthreads();
    part[t] += v;
    __syncthreads();
  }
  int run = (t == 0) ? 0 : part[t - 1];
  for (int i = lo; i < hi; ++i) {
    rs[i] = run;
    cur[i] = run;
    run += deg[i];
  }
  if (t == 1023) rs[N_NODES] = part[1023];
}

__global__ void k_scatter(const int* __restrict__ src, const int* __restrict__ dst,
                          const float* __restrict__ w, int* __restrict__ cur,
                          uint2* __restrict__ sew) {
  int e = blockIdx.x * blockDim.x + threadIdx.x;
  if (e < N_EDGES) {
    int d = dst[e];
    int p = atomicAdd(&cur[d], 1);
    sew[p] = make_uint2((unsigned)src[e], __float_as_uint(w[e]));
  }
}

// ---------------- GEMM: XW = X @ W, store bf16 ----------------
// block 256 threads, tile 64(M) x 64(N), K in 4 chunks of 64.
// AsT: [k][m] stride 68 (16B-aligned rows, spreads banks), Bs: [k][n] stride 64.

__global__ __launch_bounds__(256) void k_gemm(const float* __restrict__ x,
                                              const float* __restrict__ w,
                                              unsigned short* __restrict__ xw) {
  __shared__ float AsT[64 * 68];
  __shared__ float Bs[64 * 64];
  const int tid = threadIdx.x;
  const int tx = tid & 15;   // col quad
  const int ty = tid >> 4;   // row quad
  const int m0 = blockIdx.y * 64;
  const int n0 = blockIdx.x * 64;

  float acc[4][4];
#pragma unroll
  for (int i = 0; i < 4; ++i)
#pragma unroll
    for (int j = 0; j < 4; ++j) acc[i][j] = 0.f;

  for (int kt = 0; kt < 4; ++kt) {
    const int k0 = kt * 64;
    // A chunk 64x64 -> AsT (transposed store)
#pragma unroll
    for (int i = 0; i < 4; ++i) {
      int f = i * 256 + tid;
      int row = f >> 4;
      int c4 = f & 15;
      int m = m0 + row;
      float4 v = make_float4(0.f, 0.f, 0.f, 0.f);
      if (m < N_NODES) v = *(const float4*)(x + (size_t)m * DDIM + k0 + c4 * 4);
      AsT[(c4 * 4 + 0) * 68 + row] = v.x;
      AsT[(c4 * 4 + 1) * 68 + row] = v.y;
      AsT[(c4 * 4 + 2) * 68 + row] = v.z;
      AsT[(c4 * 4 + 3) * 68 + row] = v.w;
    }
    // B chunk 64x64 -> Bs (natural layout)
#pragma unroll
    for (int i = 0; i < 4; ++i) {
      int f = i * 256 + tid;
      int kr = f >> 4;
      int c4 = f & 15;
      float4 v = *(const float4*)(w + (size_t)(k0 + kr) * DDIM + n0 + c4 * 4);
      *(float4*)&Bs[kr * 64 + c4 * 4] = v;
    }
    __syncthreads();
#pragma unroll 8
    for (int k = 0; k < 64; ++k) {
      float4 a = *(const float4*)&AsT[k * 68 + ty * 4];
      float4 b = *(const float4*)&Bs[k * 64 + tx * 4];
      acc[0][0] += a.x * b.x; acc[0][1] += a.x * b.y; acc[0][2] += a.x * b.z; acc[0][3] += a.x * b.w;
      acc[1][0] += a.y * b.x; acc[1][1] += a.y * b.y; acc[1][2] += a.y * b.z; acc[1][3] += a.y * b.w;
      acc[2][0] += a.z * b.x; acc[2][1] += a.z * b.y; acc[2][2] += a.z * b.z; acc[2][3] += a.z * b.w;
      acc[3][0] += a.w * b.x; acc[3][1] += a.w * b.y; acc[3][2] += a.w * b.z; acc[3][3] += a.w * b.w;
    }
    __syncthreads();
  }
#pragma unroll
  for (int i = 0; i < 4; ++i) {
    int m = m0 + ty * 4 + i;
    if (m < N_NODES) {
      ushort4 h;
      h.x = f32_to_bf16_rne(acc[i][0]);
      h.y = f32_to_bf16_rne(acc[i][1]);
      h.z = f32_to_bf16_rne(acc[i][2]);
      h.w = f32_to_bf16_rne(acc[i][3]);
      *(ushort4*)(xw + (size_t)m * DDIM + n0 + tx * 4) = h;
    }
  }
}

// ---------------- Aggregation: one wave per dst node ----------------
// lane owns 4 consecutive channels; per edge: broadcast (src,w), gather 8B bf16x4.

__global__ __launch_bounds__(256) void k_aggr(const uint2* __restrict__ sew,
                                              const int* __restrict__ rs,
                                              const unsigned short* __restrict__ xw,
                                              const float* __restrict__ bias,
                                              float* __restrict__ z) {
  int wid = (blockIdx.x * blockDim.x + threadIdx.x) >> 6;
  int lane = threadIdx.x & 63;
  if (wid >= N_NODES) return;
  int beg = rs[wid];
  int end = rs[wid + 1];
  int c0 = lane * 4;
  float a0 = 0.f, a1 = 0.f, a2 = 0.f, a3 = 0.f;
  for (int p = beg; p < end; ++p) {
    uint2 ev = sew[p];
    float wgt = __uint_as_float(ev.y);
    ushort4 v = *(const ushort4*)(xw + (size_t)ev.x * DDIM + c0);
    a0 += wgt * __uint_as_float((unsigned)v.x << 16);
    a1 += wgt * __uint_as_float((unsigned)v.y << 16);
    a2 += wgt * __uint_as_float((unsigned)v.z << 16);
    a3 += wgt * __uint_as_float((unsigned)v.w << 16);
  }
  float4 b = *(const float4*)(bias + c0);
  float4 o = make_float4(a0 + b.x, a1 + b.y, a2 + b.z, a3 + b.w);
  *(float4*)(z + (size_t)wid * DDIM + c0) = o;
}

extern "C" void kernel_launch(void* const* d_in, const int* in_sizes, int n_in,
                              void* d_out, int out_size, void* d_ws, size_t ws_size,
                              hipStream_t stream) {
  const float* x = (const float*)d_in[0];
  const float* w = (const float*)d_in[1];
  const float* bias = (const float*)d_in[2];
  const int* esrc = (const int*)d_in[3];
  const int* edst = (const int*)d_in[4];
  const float* ew = (const float*)d_in[5];
  float* z = (float*)d_out;

  char* ws = (char*)d_ws;
  size_t off = 0;
  unsigned short* xw = (unsigned short*)(ws + off);
  off += (size_t)N_NODES * DDIM * 2;                       // 51,200,000
  int* deg = (int*)(ws + off);
  off += (((size_t)N_NODES * 4) + 255) / 256 * 256;        // 400,128
  int* rs = (int*)(ws + off);
  off += (((size_t)(N_NODES + 1) * 4) + 255) / 256 * 256;  // 400,128
  int* cur = (int*)(ws + off);
  off += (((size_t)N_NODES * 4) + 255) / 256 * 256;        // 400,128
  uint2* sew = (uint2*)(ws + off);
  off += (size_t)N_EDGES * 8;                              // 25,600,000
  // total ~78.0 MB

  hipMemsetAsync(deg, 0, (size_t)N_NODES * 4, stream);
  k_hist<<<(N_EDGES + 255) / 256, 256, 0, stream>>>(edst, deg);
  k_scan<<<1, 1024, 0, stream>>>(deg, rs, cur);
  k_scatter<<<(N_EDGES + 255) / 256, 256, 0, stream>>>(esrc, edst, ew, cur, sew);
  dim3 gg(4, (N_NODES + 63) / 64);
  k_gemm<<<gg, 256, 0, stream>>>(x, w, xw);
  k_aggr<<<(N_NODES * 64) / 256, 256, 0, stream>>>(sew, rs, xw, bias, z);
}

// Round 2
// 835.070 us; speedup vs baseline: 1.2574x; 1.2574x over previous
//
#include <hip/hip_runtime.h>
#include <hip/hip_bf16.h>
#include <stdint.h>

#define N_NODES 100000
#define N_EDGES 3200000
#define DDIM 256

typedef __attribute__((ext_vector_type(8))) short short8v;
typedef __attribute__((ext_vector_type(4))) float f32x4;

static __device__ __forceinline__ unsigned short f32_to_bf16_rne(float f) {
  unsigned u = __float_as_uint(f);
  unsigned rounded = u + 0x7FFFu + ((u >> 16) & 1u);
  return (unsigned short)(rounded >> 16);
}

// ---------------- CSR build ----------------

__global__ void k_hist(const int* __restrict__ dst, int* __restrict__ deg) {
  int e = blockIdx.x * blockDim.x + threadIdx.x;
  if (e < N_EDGES) atomicAdd(&deg[dst[e]], 1);
}

__global__ __launch_bounds__(1024) void k_scan(const int* __restrict__ deg,
                                               int* __restrict__ rs,
                                               int* __restrict__ cur) {
  __shared__ int part[1024];
  int t = threadIdx.x;
  const int CH = (N_NODES + 1023) / 1024;  // 98
  int lo = t * CH;
  int hi = lo + CH;
  if (hi > N_NODES) hi = N_NODES;
  if (lo > N_NODES) lo = N_NODES;
  int s = 0;
  for (int i = lo; i < hi; ++i) s += deg[i];
  part[t] = s;
  __syncthreads();
  for (int off = 1; off < 1024; off <<= 1) {
    int v = (t >= off) ? part[t - off] : 0;
    __syncthreads();
    part[t] += v;
    __syncthreads();
  }
  int run = (t == 0) ? 0 : part[t - 1];
  for (int i = lo; i < hi; ++i) {
    rs[i] = run;
    cur[i] = run;
    run += deg[i];
  }
  if (t == 1023) rs[N_NODES] = part[1023];
}

__global__ void k_scatter(const int* __restrict__ src, const int* __restrict__ dst,
                          const float* __restrict__ w, int* __restrict__ cur,
                          uint2* __restrict__ sew) {
  int e = blockIdx.x * blockDim.x + threadIdx.x;
  if (e < N_EDGES) {
    int d = dst[e];
    int p = atomicAdd(&cur[d], 1);
    sew[p] = make_uint2((unsigned)src[e], __float_as_uint(w[e]));
  }
}

// ---------------- fp32 -> bf16 conversions ----------------

__global__ __launch_bounds__(256) void k_cvtX(const float* __restrict__ x,
                                              unsigned short* __restrict__ xb) {
  int i = blockIdx.x * blockDim.x + threadIdx.x;  // one per 8 elems
  const float4* p = (const float4*)x + (size_t)i * 2;
  float4 a = p[0], b = p[1];
  uint4 o;
  o.x = (unsigned)f32_to_bf16_rne(a.x) | ((unsigned)f32_to_bf16_rne(a.y) << 16);
  o.y = (unsigned)f32_to_bf16_rne(a.z) | ((unsigned)f32_to_bf16_rne(a.w) << 16);
  o.z = (unsigned)f32_to_bf16_rne(b.x) | ((unsigned)f32_to_bf16_rne(b.y) << 16);
  o.w = (unsigned)f32_to_bf16_rne(b.z) | ((unsigned)f32_to_bf16_rne(b.w) << 16);
  *(uint4*)(xb + (size_t)i * 8) = o;
}

// Wt[n][k] = W[k][n], bf16
__global__ __launch_bounds__(256) void k_cvtW(const float* __restrict__ w,
                                              unsigned short* __restrict__ wt) {
  int i = blockIdx.x * blockDim.x + threadIdx.x;  // 65536 threads
  int k = i >> 8;
  int n = i & 255;
  wt[(size_t)n * DDIM + k] = f32_to_bf16_rne(w[(size_t)k * DDIM + n]);
}

// ---------------- GEMM: XW = Xb @ W (bf16 MFMA), output bf16 ----------------
// tile 128(M) x 64(N), BK=64, 256 threads = 4 waves (2x2), wave tile 64x32.
// LDS linear dest via global_load_lds; XOR swizzle applied on the global
// source chunk index and on the ds_read address (both-sides rule).

__global__ __launch_bounds__(256) void k_gemm(const unsigned short* __restrict__ xb,
                                              const unsigned short* __restrict__ wt,
                                              unsigned short* __restrict__ xw) {
  __shared__ unsigned short As[128 * 64];  // [m][k] 16 KB
  __shared__ unsigned short Bs[64 * 64];   // [n][k] 8 KB
  const int t = threadIdx.x;
  const int lane = t & 63;
  const int wid = t >> 6;
  const int wr = wid >> 1;  // 0..1
  const int wc = wid & 1;   // 0..1
  const int m0 = blockIdx.x * 128;
  const int n0 = blockIdx.y * 64;

  f32x4 acc[4][2] = {};

  const int sr = t >> 3;  // 0..31 staging row
  const int sc = t & 7;   // staging chunk

  for (int kt = 0; kt < 4; ++kt) {
    const int k0 = kt * 64;
#pragma unroll
    for (int i = 0; i < 4; ++i) {
      int r = i * 32 + sr;
      int m = m0 + r;
      if (m > N_NODES - 1) m = N_NODES - 1;
      int cc = sc ^ (r & 7);
      const unsigned short* src = xb + (size_t)m * DDIM + k0 + cc * 8;
      __builtin_amdgcn_global_load_lds(
          (const __attribute__((address_space(1))) void*)src,
          (__attribute__((address_space(3))) void*)((char*)As + i * 4096 + t * 16),
          16, 0, 0);
    }
#pragma unroll
    for (int i = 0; i < 2; ++i) {
      int r = i * 32 + sr;
      int cc = sc ^ (r & 7);
      const unsigned short* src = wt + (size_t)(n0 + r) * DDIM + k0 + cc * 8;
      __builtin_amdgcn_global_load_lds(
          (const __attribute__((address_space(1))) void*)src,
          (__attribute__((address_space(3))) void*)((char*)Bs + i * 4096 + t * 16),
          16, 0, 0);
    }
    __syncthreads();

    const int kg = lane >> 4;     // 0..3
    const int rl = lane & 15;
#pragma unroll
    for (int ks = 0; ks < 2; ++ks) {
      const int colbyte = ks * 64 + kg * 16;
      short8v af[4], bfr[2];
#pragma unroll
      for (int mi = 0; mi < 4; ++mi) {
        int row = wr * 64 + mi * 16 + rl;
        int b = row * 128 + (colbyte ^ ((row & 7) << 4));
        af[mi] = *(const short8v*)((const char*)As + b);
      }
#pragma unroll
      for (int ni = 0; ni < 2; ++ni) {
        int row = wc * 32 + ni * 16 + rl;
        int b = row * 128 + (colbyte ^ ((row & 7) << 4));
        bfr[ni] = *(const short8v*)((const char*)Bs + b);
      }
#pragma unroll
      for (int mi = 0; mi < 4; ++mi)
#pragma unroll
        for (int ni = 0; ni < 2; ++ni)
          acc[mi][ni] = __builtin_amdgcn_mfma_f32_16x16x32_bf16(af[mi], bfr[ni], acc[mi][ni], 0, 0, 0);
    }
    __syncthreads();
  }

  // epilogue: C/D layout col=lane&15, row=(lane>>4)*4+reg
  const int rbase = (lane >> 4) * 4;
  const int ncol = lane & 15;
#pragma unroll
  for (int mi = 0; mi < 4; ++mi) {
#pragma unroll
    for (int ni = 0; ni < 2; ++ni) {
      int n = n0 + wc * 32 + ni * 16 + ncol;
#pragma unroll
      for (int r = 0; r < 4; ++r) {
        int m = m0 + wr * 64 + mi * 16 + rbase + r;
        if (m < N_NODES)
          xw[(size_t)m * DDIM + n] = f32_to_bf16_rne(acc[mi][ni][r]);
      }
    }
  }
}

// ---------------- Aggregation: one wave per dst node, unroll 4 ----------------

__global__ __launch_bounds__(256) void k_aggr(const uint2* __restrict__ sew,
                                              const int* __restrict__ rs,
                                              const unsigned short* __restrict__ xw,
                                              const float* __restrict__ bias,
                                              float* __restrict__ z) {
  int wid = (blockIdx.x * blockDim.x + threadIdx.x) >> 6;
  int lane = threadIdx.x & 63;
  if (wid >= N_NODES) return;
  int beg = rs[wid];
  int end = rs[wid + 1];
  int c0 = lane * 4;
  float a0 = 0.f, a1 = 0.f, a2 = 0.f, a3 = 0.f;
  int p = beg;
  for (; p + 4 <= end; p += 4) {
    uint2 e0 = sew[p];
    uint2 e1 = sew[p + 1];
    uint2 e2 = sew[p + 2];
    uint2 e3 = sew[p + 3];
    ushort4 v0 = *(const ushort4*)(xw + (size_t)e0.x * DDIM + c0);
    ushort4 v1 = *(const ushort4*)(xw + (size_t)e1.x * DDIM + c0);
    ushort4 v2 = *(const ushort4*)(xw + (size_t)e2.x * DDIM + c0);
    ushort4 v3 = *(const ushort4*)(xw + (size_t)e3.x * DDIM + c0);
    float w0 = __uint_as_float(e0.y);
    float w1 = __uint_as_float(e1.y);
    float w2 = __uint_as_float(e2.y);
    float w3 = __uint_as_float(e3.y);
    a0 += w0 * __uint_as_float((unsigned)v0.x << 16);
    a1 += w0 * __uint_as_float((unsigned)v0.y << 16);
    a2 += w0 * __uint_as_float((unsigned)v0.z << 16);
    a3 += w0 * __uint_as_float((unsigned)v0.w << 16);
    a0 += w1 * __uint_as_float((unsigned)v1.x << 16);
    a1 += w1 * __uint_as_float((unsigned)v1.y << 16);
    a2 += w1 * __uint_as_float((unsigned)v1.z << 16);
    a3 += w1 * __uint_as_float((unsigned)v1.w << 16);
    a0 += w2 * __uint_as_float((unsigned)v2.x << 16);
    a1 += w2 * __uint_as_float((unsigned)v2.y << 16);
    a2 += w2 * __uint_as_float((unsigned)v2.z << 16);
    a3 += w2 * __uint_as_float((unsigned)v2.w << 16);
    a0 += w3 * __uint_as_float((unsigned)v3.x << 16);
    a1 += w3 * __uint_as_float((unsigned)v3.y << 16);
    a2 += w3 * __uint_as_float((unsigned)v3.z << 16);
    a3 += w3 * __uint_as_float((unsigned)v3.w << 16);
  }
  for (; p < end; ++p) {
    uint2 ev = sew[p];
    float wgt = __uint_as_float(ev.y);
    ushort4 v = *(const ushort4*)(xw + (size_t)ev.x * DDIM + c0);
    a0 += wgt * __uint_as_float((unsigned)v.x << 16);
    a1 += wgt * __uint_as_float((unsigned)v.y << 16);
    a2 += wgt * __uint_as_float((unsigned)v.z << 16);
    a3 += wgt * __uint_as_float((unsigned)v.w << 16);
  }
  float4 b = *(const float4*)(bias + c0);
  float4 o = make_float4(a0 + b.x, a1 + b.y, a2 + b.z, a3 + b.w);
  *(float4*)(z + (size_t)wid * DDIM + c0) = o;
}

extern "C" void kernel_launch(void* const* d_in, const int* in_sizes, int n_in,
                              void* d_out, int out_size, void* d_ws, size_t ws_size,
                              hipStream_t stream) {
  const float* x = (const float*)d_in[0];
  const float* w = (const float*)d_in[1];
  const float* bias = (const float*)d_in[2];
  const int* esrc = (const int*)d_in[3];
  const int* edst = (const int*)d_in[4];
  const float* ew = (const float*)d_in[5];
  float* z = (float*)d_out;

  char* ws = (char*)d_ws;
  size_t off = 0;
  unsigned short* xw = (unsigned short*)(ws + off);
  off += (size_t)N_NODES * DDIM * 2;                       // 51.2 MB
  unsigned short* xb = (unsigned short*)(ws + off);
  off += (size_t)N_NODES * DDIM * 2;                       // 51.2 MB
  unsigned short* wt = (unsigned short*)(ws + off);
  off += (size_t)DDIM * DDIM * 2;                          // 128 KB
  int* deg = (int*)(ws + off);
  off += (((size_t)N_NODES * 4) + 255) / 256 * 256;
  int* rs = (int*)(ws + off);
  off += (((size_t)(N_NODES + 1) * 4) + 255) / 256 * 256;
  int* cur = (int*)(ws + off);
  off += (((size_t)N_NODES * 4) + 255) / 256 * 256;
  uint2* sew = (uint2*)(ws + off);
  off += (size_t)N_EDGES * 8;                              // 25.6 MB
  // total ~130 MB

  hipMemsetAsync(deg, 0, (size_t)N_NODES * 4, stream);
  k_hist<<<(N_EDGES + 255) / 256, 256, 0, stream>>>(edst, deg);
  k_scan<<<1, 1024, 0, stream>>>(deg, rs, cur);
  k_scatter<<<(N_EDGES + 255) / 256, 256, 0, stream>>>(esrc, edst, ew, cur, sew);
  k_cvtX<<<(N_NODES * DDIM / 8 + 255) / 256, 256, 0, stream>>>(x, xb);
  k_cvtW<<<(DDIM * DDIM + 255) / 256, 256, 0, stream>>>(w, wt);
  dim3 gg((N_NODES + 127) / 128, DDIM / 64);
  k_gemm<<<gg, 256, 0, stream>>>(xb, wt, xw);
  k_aggr<<<(N_NODES * 64) / 256, 256, 0, stream>>>(sew, rs, xw, bias, z);
}

// Round 3
// 585.647 us; speedup vs baseline: 1.7929x; 1.4259x over previous
//
#include <hip/hip_runtime.h>
#include <hip/hip_bf16.h>
#include <stdint.h>

#define N_NODES 100000
#define N_EDGES 3200000
#define DDIM 256
#define NB 782        // ceil(100000 / 128) buckets of 128 dst nodes
#define CAP 6144      // LDS sort capacity per bucket (mean 4092, sd 64)

typedef __attribute__((ext_vector_type(8))) short short8v;
typedef __attribute__((ext_vector_type(4))) float f32x4;

static __device__ __forceinline__ unsigned short f32_to_bf16_rne(float f) {
  unsigned u = __float_as_uint(f);
  unsigned rounded = u + 0x7FFFu + ((u >> 16) & 1u);
  return (unsigned short)(rounded >> 16);
}

static __device__ __forceinline__ float bf16_to_f32(unsigned short h) {
  return __uint_as_float((unsigned)h << 16);
}

// ---------------- bucket histogram (LDS-staged) ----------------

__global__ __launch_bounds__(256) void k_bhist(const int* __restrict__ dst,
                                               int* __restrict__ bcnt) {
  __shared__ int h[NB];
  for (int i = threadIdx.x; i < NB; i += 256) h[i] = 0;
  __syncthreads();
  const int stride = gridDim.x * 256;
  for (int e = blockIdx.x * 256 + threadIdx.x; e < N_EDGES; e += stride)
    atomicAdd(&h[dst[e] >> 7], 1);
  __syncthreads();
  for (int i = threadIdx.x; i < NB; i += 256) {
    int v = h[i];
    if (v) atomicAdd(&bcnt[i * 16], v);   // cursors padded: 1 per 64B line
  }
}

// ---------------- bucket offsets scan ----------------

__global__ __launch_bounds__(1024) void k_bscan(const int* __restrict__ bcnt,
                                                int* __restrict__ boff,
                                                int* __restrict__ bcur) {
  __shared__ int part[1024];
  int t = threadIdx.x;
  part[t] = (t < NB) ? bcnt[t * 16] : 0;
  __syncthreads();
  for (int off = 1; off < 1024; off <<= 1) {
    int v = (t >= off) ? part[t - off] : 0;
    __syncthreads();
    part[t] += v;
    __syncthreads();
  }
  if (t < NB) {
    int excl = (t == 0) ? 0 : part[t - 1];
    boff[t] = excl;
    bcur[t * 16] = excl;
  }
  if (t == 0) boff[NB] = N_EDGES;
}

// ---------------- bin edges into bucket regions ----------------
// record: (dst_local[7b] << 17) | src[17b], edge weight bits

__global__ void k_bin(const int* __restrict__ src, const int* __restrict__ dst,
                      const float* __restrict__ w, int* __restrict__ bcur,
                      uint2* __restrict__ bin) {
  int e = blockIdx.x * blockDim.x + threadIdx.x;
  if (e < N_EDGES) {
    int d = dst[e];
    int p = atomicAdd(&bcur[(d >> 7) * 16], 1);
    bin[p] = make_uint2(((unsigned)(d & 127) << 17) | (unsigned)src[e],
                        __float_as_uint(w[e]));
  }
}

// ---------------- fp32 -> bf16 conversions ----------------

__global__ __launch_bounds__(256) void k_cvtX(const float* __restrict__ x,
                                              unsigned short* __restrict__ xb) {
  int i = blockIdx.x * blockDim.x + threadIdx.x;  // one per 8 elems
  const float4* p = (const float4*)x + (size_t)i * 2;
  float4 a = p[0], b = p[1];
  uint4 o;
  o.x = (unsigned)f32_to_bf16_rne(a.x) | ((unsigned)f32_to_bf16_rne(a.y) << 16);
  o.y = (unsigned)f32_to_bf16_rne(a.z) | ((unsigned)f32_to_bf16_rne(a.w) << 16);
  o.z = (unsigned)f32_to_bf16_rne(b.x) | ((unsigned)f32_to_bf16_rne(b.y) << 16);
  o.w = (unsigned)f32_to_bf16_rne(b.z) | ((unsigned)f32_to_bf16_rne(b.w) << 16);
  *(uint4*)(xb + (size_t)i * 8) = o;
}

// Wt[n][k] = W[k][n], bf16
__global__ __launch_bounds__(256) void k_cvtW(const float* __restrict__ w,
                                              unsigned short* __restrict__ wt) {
  int i = blockIdx.x * blockDim.x + threadIdx.x;
  int k = i >> 8;
  int n = i & 255;
  wt[(size_t)n * DDIM + k] = f32_to_bf16_rne(w[(size_t)k * DDIM + n]);
}

// ---------------- GEMM: XW = Xb @ W (bf16 MFMA), output bf16 ----------------

__global__ __launch_bounds__(256) void k_gemm(const unsigned short* __restrict__ xb,
                                              const unsigned short* __restrict__ wt,
                                              unsigned short* __restrict__ xw) {
  __shared__ unsigned short As[128 * 64];  // [m][k] 16 KB
  __shared__ unsigned short Bs[64 * 64];   // [n][k] 8 KB
  const int t = threadIdx.x;
  const int lane = t & 63;
  const int wid = t >> 6;
  const int wr = wid >> 1;
  const int wc = wid & 1;
  const int m0 = blockIdx.x * 128;
  const int n0 = blockIdx.y * 64;

  f32x4 acc[4][2] = {};

  const int sr = t >> 3;
  const int sc = t & 7;

  for (int kt = 0; kt < 4; ++kt) {
    const int k0 = kt * 64;
#pragma unroll
    for (int i = 0; i < 4; ++i) {
      int r = i * 32 + sr;
      int m = m0 + r;
      if (m > N_NODES - 1) m = N_NODES - 1;
      int cc = sc ^ (r & 7);
      const unsigned short* src = xb + (size_t)m * DDIM + k0 + cc * 8;
      __builtin_amdgcn_global_load_lds(
          (const __attribute__((address_space(1))) void*)src,
          (__attribute__((address_space(3))) void*)((char*)As + i * 4096 + t * 16),
          16, 0, 0);
    }
#pragma unroll
    for (int i = 0; i < 2; ++i) {
      int r = i * 32 + sr;
      int cc = sc ^ (r & 7);
      const unsigned short* src = wt + (size_t)(n0 + r) * DDIM + k0 + cc * 8;
      __builtin_amdgcn_global_load_lds(
          (const __attribute__((address_space(1))) void*)src,
          (__attribute__((address_space(3))) void*)((char*)Bs + i * 4096 + t * 16),
          16, 0, 0);
    }
    __syncthreads();

    const int kg = lane >> 4;
    const int rl = lane & 15;
#pragma unroll
    for (int ks = 0; ks < 2; ++ks) {
      const int colbyte = ks * 64 + kg * 16;
      short8v af[4], bfr[2];
#pragma unroll
      for (int mi = 0; mi < 4; ++mi) {
        int row = wr * 64 + mi * 16 + rl;
        int b = row * 128 + (colbyte ^ ((row & 7) << 4));
        af[mi] = *(const short8v*)((const char*)As + b);
      }
#pragma unroll
      for (int ni = 0; ni < 2; ++ni) {
        int row = wc * 32 + ni * 16 + rl;
        int b = row * 128 + (colbyte ^ ((row & 7) << 4));
        bfr[ni] = *(const short8v*)((const char*)Bs + b);
      }
#pragma unroll
      for (int mi = 0; mi < 4; ++mi)
#pragma unroll
        for (int ni = 0; ni < 2; ++ni)
          acc[mi][ni] = __builtin_amdgcn_mfma_f32_16x16x32_bf16(af[mi], bfr[ni], acc[mi][ni], 0, 0, 0);
    }
    __syncthreads();
  }

  const int rbase = (lane >> 4) * 4;
  const int ncol = lane & 15;
#pragma unroll
  for (int mi = 0; mi < 4; ++mi) {
#pragma unroll
    for (int ni = 0; ni < 2; ++ni) {
      int n = n0 + wc * 32 + ni * 16 + ncol;
#pragma unroll
      for (int r = 0; r < 4; ++r) {
        int m = m0 + wr * 64 + mi * 16 + rbase + r;
        if (m < N_NODES)
          xw[(size_t)m * DDIM + n] = f32_to_bf16_rne(acc[mi][ni][r]);
      }
    }
  }
}

// ---------------- bucket sort (LDS) + aggregate ----------------
// one block of 512 per bucket; counting-sort bucket's records in LDS,
// then one wave per 16 local nodes aggregates, lane owns 4 channels.

__global__ __launch_bounds__(512) void k_baggr(const uint2* __restrict__ bin,
                                               const int* __restrict__ boff,
                                               const unsigned short* __restrict__ xw,
                                               const float* __restrict__ bias,
                                               float* __restrict__ z) {
  __shared__ uint2 srt[CAP];   // 48 KB
  __shared__ int lh[129];
  __shared__ int lc[128];
  const int b = blockIdx.x;
  const int t = threadIdx.x;
  const int beg = boff[b];
  const int cnt = boff[b + 1] - beg;
  const int nbase = b << 7;
  int nmax = N_NODES - nbase;
  if (nmax > 128) nmax = 128;

  if (t < 129) lh[t] = 0;
  __syncthreads();

  const int wid = t >> 6;
  const int lane = t & 63;
  const int c0 = lane * 4;
  const float4 bv = *(const float4*)(bias + c0);

  if (cnt <= CAP) {
    uint2 rec[12];
    int nrec = 0;
#pragma unroll
    for (int j = 0; j < 12; ++j) {
      int p = t + j * 512;
      if (p < cnt) {
        rec[j] = bin[beg + p];
        atomicAdd(&lh[(rec[j].x >> 17) + 1], 1);
        nrec = j + 1;
      }
    }
    __syncthreads();
    if (wid == 0) {  // wave-parallel inclusive scan of lh[1..128]
      int v0 = lh[lane + 1];
      int v1 = lh[lane + 65];
#pragma unroll
      for (int d = 1; d < 64; d <<= 1) {
        int u = __shfl_up(v0, d);
        if (lane >= d) v0 += u;
      }
      int tot0 = __shfl(v0, 63);
#pragma unroll
      for (int d = 1; d < 64; d <<= 1) {
        int u = __shfl_up(v1, d);
        if (lane >= d) v1 += u;
      }
      v1 += tot0;
      lh[lane + 1] = v0;
      lh[lane + 65] = v1;
    }
    __syncthreads();
    if (t < 128) lc[t] = lh[t];
    __syncthreads();
#pragma unroll
    for (int j = 0; j < 12; ++j) {
      if (j < nrec) {
        int q = atomicAdd(&lc[rec[j].x >> 17], 1);
        srt[q] = make_uint2(rec[j].x & 0x1FFFFu, rec[j].y);
      }
    }
    __syncthreads();

#pragma unroll 1
    for (int i = wid * 16; i < wid * 16 + 16; ++i) {
      if (i >= nmax) break;
      int s = lh[i];
      int e2 = lh[i + 1];
      float a0 = 0.f, a1 = 0.f, a2 = 0.f, a3 = 0.f;
      int p = s;
      for (; p + 4 <= e2; p += 4) {
        uint2 r0 = srt[p];
        uint2 r1 = srt[p + 1];
        uint2 r2 = srt[p + 2];
        uint2 r3 = srt[p + 3];
        ushort4 v0 = *(const ushort4*)(xw + (size_t)r0.x * DDIM + c0);
        ushort4 v1 = *(const ushort4*)(xw + (size_t)r1.x * DDIM + c0);
        ushort4 v2 = *(const ushort4*)(xw + (size_t)r2.x * DDIM + c0);
        ushort4 v3 = *(const ushort4*)(xw + (size_t)r3.x * DDIM + c0);
        float w0 = __uint_as_float(r0.y);
        float w1 = __uint_as_float(r1.y);
        float w2 = __uint_as_float(r2.y);
        float w3 = __uint_as_float(r3.y);
        a0 += w0 * bf16_to_f32(v0.x); a1 += w0 * bf16_to_f32(v0.y);
        a2 += w0 * bf16_to_f32(v0.z); a3 += w0 * bf16_to_f32(v0.w);
        a0 += w1 * bf16_to_f32(v1.x); a1 += w1 * bf16_to_f32(v1.y);
        a2 += w1 * bf16_to_f32(v1.z); a3 += w1 * bf16_to_f32(v1.w);
        a0 += w2 * bf16_to_f32(v2.x); a1 += w2 * bf16_to_f32(v2.y);
        a2 += w2 * bf16_to_f32(v2.z); a3 += w2 * bf16_to_f32(v2.w);
        a0 += w3 * bf16_to_f32(v3.x); a1 += w3 * bf16_to_f32(v3.y);
        a2 += w3 * bf16_to_f32(v3.z); a3 += w3 * bf16_to_f32(v3.w);
      }
      for (; p < e2; ++p) {
        uint2 r = srt[p];
        float wgt = __uint_as_float(r.y);
        ushort4 v = *(const ushort4*)(xw + (size_t)r.x * DDIM + c0);
        a0 += wgt * bf16_to_f32(v.x);
        a1 += wgt * bf16_to_f32(v.y);
        a2 += wgt * bf16_to_f32(v.z);
        a3 += wgt * bf16_to_f32(v.w);
      }
      *(float4*)(z + (size_t)(nbase + i) * DDIM + c0) =
          make_float4(a0 + bv.x, a1 + bv.y, a2 + bv.z, a3 + bv.w);
    }
  } else {
    // fallback (data-safety; statistically unreachable): scan all records per node
#pragma unroll 1
    for (int i = wid * 16; i < wid * 16 + 16; ++i) {
      if (i >= nmax) break;
      float a0 = 0.f, a1 = 0.f, a2 = 0.f, a3 = 0.f;
      for (int p = 0; p < cnt; ++p) {
        uint2 r = bin[beg + p];
        if ((int)(r.x >> 17) == i) {
          float wgt = __uint_as_float(r.y);
          ushort4 v = *(const ushort4*)(xw + (size_t)(r.x & 0x1FFFFu) * DDIM + c0);
          a0 += wgt * bf16_to_f32(v.x);
          a1 += wgt * bf16_to_f32(v.y);
          a2 += wgt * bf16_to_f32(v.z);
          a3 += wgt * bf16_to_f32(v.w);
        }
      }
      *(float4*)(z + (size_t)(nbase + i) * DDIM + c0) =
          make_float4(a0 + bv.x, a1 + bv.y, a2 + bv.z, a3 + bv.w);
    }
  }
}

extern "C" void kernel_launch(void* const* d_in, const int* in_sizes, int n_in,
                              void* d_out, int out_size, void* d_ws, size_t ws_size,
                              hipStream_t stream) {
  const float* x = (const float*)d_in[0];
  const float* w = (const float*)d_in[1];
  const float* bias = (const float*)d_in[2];
  const int* esrc = (const int*)d_in[3];
  const int* edst = (const int*)d_in[4];
  const float* ew = (const float*)d_in[5];
  float* z = (float*)d_out;

  char* ws = (char*)d_ws;
  size_t off = 0;
  unsigned short* xw = (unsigned short*)(ws + off);
  off += (size_t)N_NODES * DDIM * 2;                        // 51.2 MB
  unsigned short* xb = (unsigned short*)(ws + off);
  off += (size_t)N_NODES * DDIM * 2;                        // 51.2 MB
  unsigned short* wt = (unsigned short*)(ws + off);
  off += (size_t)DDIM * DDIM * 2;                           // 128 KB
  int* bcnt = (int*)(ws + off);
  off += (size_t)NB * 16 * 4;                               // 50 KB (line-padded)
  int* boff = (int*)(ws + off);
  off += (((size_t)(NB + 1) * 4) + 255) / 256 * 256;
  int* bcur = (int*)(ws + off);
  off += (size_t)NB * 16 * 4;                               // 50 KB (line-padded)
  uint2* bin = (uint2*)(ws + off);
  off += (size_t)N_EDGES * 8;                               // 25.6 MB

  hipMemsetAsync(bcnt, 0, (size_t)NB * 16 * 4, stream);
  k_bhist<<<512, 256, 0, stream>>>(edst, bcnt);
  k_bscan<<<1, 1024, 0, stream>>>(bcnt, boff, bcur);
  k_bin<<<(N_EDGES + 255) / 256, 256, 0, stream>>>(esrc, edst, ew, bcur, bin);
  k_cvtX<<<(N_NODES * DDIM / 8 + 255) / 256, 256, 0, stream>>>(x, xb);
  k_cvtW<<<(DDIM * DDIM + 255) / 256, 256, 0, stream>>>(w, wt);
  dim3 gg((N_NODES + 127) / 128, DDIM / 64);
  k_gemm<<<gg, 256, 0, stream>>>(xb, wt, xw);
  k_baggr<<<NB, 512, 0, stream>>>(bin, boff, xw, bias, z);
}

// Round 4
// 484.984 us; speedup vs baseline: 2.1650x; 1.2076x over previous
//
#include <hip/hip_runtime.h>
#include <hip/hip_bf16.h>
#include <stdint.h>

#define N_NODES 100000
#define N_EDGES 3200000
#define DDIM 256
#define NB 782        // ceil(100000 / 128) buckets of 128 dst nodes
#define CAP 5632      // LDS sort capacity per bucket (mean 4092, sd 64; 24 sigma)
#define BINBLK 4096   // edges per k_bin block

typedef __attribute__((ext_vector_type(8))) short short8v;
typedef __attribute__((ext_vector_type(4))) float f32x4;

static __device__ __forceinline__ unsigned short f32_to_bf16_rne(float f) {
  unsigned u = __float_as_uint(f);
  unsigned rounded = u + 0x7FFFu + ((u >> 16) & 1u);
  return (unsigned short)(rounded >> 16);
}

static __device__ __forceinline__ float bf16_to_f32(unsigned short h) {
  return __uint_as_float((unsigned)h << 16);
}

// bf16 pair unpack from packed u32
static __device__ __forceinline__ float bfLO(unsigned v) { return __uint_as_float(v << 16); }
static __device__ __forceinline__ float bfHI(unsigned v) { return __uint_as_float(v & 0xFFFF0000u); }

// ---------------- bucket histogram (LDS-staged) ----------------

__global__ __launch_bounds__(256) void k_bhist(const int* __restrict__ dst,
                                               int* __restrict__ bcnt) {
  __shared__ int h[NB];
  for (int i = threadIdx.x; i < NB; i += 256) h[i] = 0;
  __syncthreads();
  const int stride = gridDim.x * 256;
  for (int e = blockIdx.x * 256 + threadIdx.x; e < N_EDGES; e += stride)
    atomicAdd(&h[dst[e] >> 7], 1);
  __syncthreads();
  for (int i = threadIdx.x; i < NB; i += 256) {
    int v = h[i];
    if (v) atomicAdd(&bcnt[i * 16], v);   // cursors padded: 1 per 64B line
  }
}

// ---------------- bucket offsets scan ----------------

__global__ __launch_bounds__(1024) void k_bscan(const int* __restrict__ bcnt,
                                                int* __restrict__ boff,
                                                int* __restrict__ bcur) {
  __shared__ int part[1024];
  int t = threadIdx.x;
  part[t] = (t < NB) ? bcnt[t * 16] : 0;
  __syncthreads();
  for (int off = 1; off < 1024; off <<= 1) {
    int v = (t >= off) ? part[t - off] : 0;
    __syncthreads();
    part[t] += v;
    __syncthreads();
  }
  if (t < NB) {
    int excl = (t == 0) ? 0 : part[t - 1];
    boff[t] = excl;
    bcur[t * 16] = excl;
  }
  if (t == 0) boff[NB] = N_EDGES;
}

// ---------------- bin edges: block-level LDS binning ----------------
// each block owns BINBLK contiguous edges; 1 global atomic per (block,bucket).

__global__ __launch_bounds__(256) void k_bin(const int* __restrict__ src,
                                             const int* __restrict__ dst,
                                             const float* __restrict__ w,
                                             int* __restrict__ bcur,
                                             uint2* __restrict__ bin) {
  __shared__ int hist[NB];   // counts, then cursors
  const int t = threadIdx.x;
  const int e0 = blockIdx.x * BINBLK;
  int n = N_EDGES - e0;
  if (n > BINBLK) n = BINBLK;
  for (int i = t; i < NB; i += 256) hist[i] = 0;
  __syncthreads();
  int myd[16];
#pragma unroll
  for (int j = 0; j < 16; ++j) {
    int p = j * 256 + t;
    if (p < n) {
      myd[j] = dst[e0 + p];
      atomicAdd(&hist[myd[j] >> 7], 1);
    } else {
      myd[j] = -1;
    }
  }
  __syncthreads();
  for (int i = t; i < NB; i += 256) {
    int h = hist[i];
    hist[i] = h ? atomicAdd(&bcur[i * 16], h) : 0;   // hist becomes cursor
  }
  __syncthreads();
#pragma unroll
  for (int j = 0; j < 16; ++j) {
    int p = j * 256 + t;
    if (p < n) {
      int d = myd[j];
      int q = atomicAdd(&hist[d >> 7], 1);
      bin[q] = make_uint2(((unsigned)(d & 127) << 17) | (unsigned)src[e0 + p],
                          __float_as_uint(w[e0 + p]));
    }
  }
}

// ---------------- fp32 -> bf16 conversions ----------------

__global__ __launch_bounds__(256) void k_cvtX(const float* __restrict__ x,
                                              unsigned short* __restrict__ xb) {
  int i = blockIdx.x * blockDim.x + threadIdx.x;  // one per 8 elems
  const float4* p = (const float4*)x + (size_t)i * 2;
  float4 a = p[0], b = p[1];
  uint4 o;
  o.x = (unsigned)f32_to_bf16_rne(a.x) | ((unsigned)f32_to_bf16_rne(a.y) << 16);
  o.y = (unsigned)f32_to_bf16_rne(a.z) | ((unsigned)f32_to_bf16_rne(a.w) << 16);
  o.z = (unsigned)f32_to_bf16_rne(b.x) | ((unsigned)f32_to_bf16_rne(b.y) << 16);
  o.w = (unsigned)f32_to_bf16_rne(b.z) | ((unsigned)f32_to_bf16_rne(b.w) << 16);
  *(uint4*)(xb + (size_t)i * 8) = o;
}

// Wt[n][k] = W[k][n], bf16
__global__ __launch_bounds__(256) void k_cvtW(const float* __restrict__ w,
                                              unsigned short* __restrict__ wt) {
  int i = blockIdx.x * blockDim.x + threadIdx.x;
  int k = i >> 8;
  int n = i & 255;
  wt[(size_t)n * DDIM + k] = f32_to_bf16_rne(w[(size_t)k * DDIM + n]);
}

// ---------------- GEMM: XW = Xb @ W (bf16 MFMA), output bf16 ----------------

__global__ __launch_bounds__(256) void k_gemm(const unsigned short* __restrict__ xb,
                                              const unsigned short* __restrict__ wt,
                                              unsigned short* __restrict__ xw) {
  __shared__ unsigned short As[128 * 64];  // [m][k] 16 KB
  __shared__ unsigned short Bs[64 * 64];   // [n][k] 8 KB
  const int t = threadIdx.x;
  const int lane = t & 63;
  const int wid = t >> 6;
  const int wr = wid >> 1;
  const int wc = wid & 1;
  const int m0 = blockIdx.x * 128;
  const int n0 = blockIdx.y * 64;

  f32x4 acc[4][2] = {};

  const int sr = t >> 3;
  const int sc = t & 7;

  for (int kt = 0; kt < 4; ++kt) {
    const int k0 = kt * 64;
#pragma unroll
    for (int i = 0; i < 4; ++i) {
      int r = i * 32 + sr;
      int m = m0 + r;
      if (m > N_NODES - 1) m = N_NODES - 1;
      int cc = sc ^ (r & 7);
      const unsigned short* src = xb + (size_t)m * DDIM + k0 + cc * 8;
      __builtin_amdgcn_global_load_lds(
          (const __attribute__((address_space(1))) void*)src,
          (__attribute__((address_space(3))) void*)((char*)As + i * 4096 + t * 16),
          16, 0, 0);
    }
#pragma unroll
    for (int i = 0; i < 2; ++i) {
      int r = i * 32 + sr;
      int cc = sc ^ (r & 7);
      const unsigned short* src = wt + (size_t)(n0 + r) * DDIM + k0 + cc * 8;
      __builtin_amdgcn_global_load_lds(
          (const __attribute__((address_space(1))) void*)src,
          (__attribute__((address_space(3))) void*)((char*)Bs + i * 4096 + t * 16),
          16, 0, 0);
    }
    __syncthreads();

    const int kg = lane >> 4;
    const int rl = lane & 15;
#pragma unroll
    for (int ks = 0; ks < 2; ++ks) {
      const int colbyte = ks * 64 + kg * 16;
      short8v af[4], bfr[2];
#pragma unroll
      for (int mi = 0; mi < 4; ++mi) {
        int row = wr * 64 + mi * 16 + rl;
        int b = row * 128 + (colbyte ^ ((row & 7) << 4));
        af[mi] = *(const short8v*)((const char*)As + b);
      }
#pragma unroll
      for (int ni = 0; ni < 2; ++ni) {
        int row = wc * 32 + ni * 16 + rl;
        int b = row * 128 + (colbyte ^ ((row & 7) << 4));
        bfr[ni] = *(const short8v*)((const char*)Bs + b);
      }
#pragma unroll
      for (int mi = 0; mi < 4; ++mi)
#pragma unroll
        for (int ni = 0; ni < 2; ++ni)
          acc[mi][ni] = __builtin_amdgcn_mfma_f32_16x16x32_bf16(af[mi], bfr[ni], acc[mi][ni], 0, 0, 0);
    }
    __syncthreads();
  }

  const int rbase = (lane >> 4) * 4;
  const int ncol = lane & 15;
#pragma unroll
  for (int mi = 0; mi < 4; ++mi) {
#pragma unroll
    for (int ni = 0; ni < 2; ++ni) {
      int n = n0 + wc * 32 + ni * 16 + ncol;
#pragma unroll
      for (int r = 0; r < 4; ++r) {
        int m = m0 + wr * 64 + mi * 16 + rbase + r;
        if (m < N_NODES)
          xw[(size_t)m * DDIM + n] = f32_to_bf16_rne(acc[mi][ni][r]);
      }
    }
  }
}

// ---------------- bucket sort (LDS) + aggregate ----------------
// one block of 512 per bucket; counting-sort records in LDS, then one wave
// per 16 local nodes aggregates. Edge-pair mode: half-wave h handles edge
// p+h; lane owns 8 channels via 16B loads; cross-half shfl_xor combine.

__global__ __launch_bounds__(512, 6) void k_baggr(const uint2* __restrict__ bin,
                                                  const int* __restrict__ boff,
                                                  const unsigned short* __restrict__ xw,
                                                  const float* __restrict__ bias,
                                                  float* __restrict__ z) {
  __shared__ uint2 srt[CAP];   // 44 KB
  __shared__ int lh[129];
  __shared__ int lc[128];
  const int b = blockIdx.x;
  const int t = threadIdx.x;
  const int beg = boff[b];
  const int cnt = boff[b + 1] - beg;
  const int nbase = b << 7;
  int nmax = N_NODES - nbase;
  if (nmax > 128) nmax = 128;

  if (t < 129) lh[t] = 0;
  __syncthreads();

  const int wid = t >> 6;
  const int lane = t & 63;
  const int h = lane >> 5;       // edge-pair half
  const int l5 = lane & 31;
  const int g0 = l5 * 8;         // gather col (8 ch, 16B)
  const int c0 = g0 + h * 4;     // write col (4 ch)
  const float4 bv = *(const float4*)(bias + c0);

  if (cnt <= CAP) {
    uint2 rec[11];               // CAP/512 = 11
    int nrec = 0;
#pragma unroll
    for (int j = 0; j < 11; ++j) {
      int p = t + j * 512;
      if (p < cnt) {
        rec[j] = bin[beg + p];
        atomicAdd(&lh[(rec[j].x >> 17) + 1], 1);
        nrec = j + 1;
      }
    }
    __syncthreads();
    if (wid == 0) {  // wave-parallel inclusive scan of lh[1..128]
      int v0 = lh[lane + 1];
      int v1 = lh[lane + 65];
#pragma unroll
      for (int d = 1; d < 64; d <<= 1) {
        int u = __shfl_up(v0, d);
        if (lane >= d) v0 += u;
      }
      int tot0 = __shfl(v0, 63);
#pragma unroll
      for (int d = 1; d < 64; d <<= 1) {
        int u = __shfl_up(v1, d);
        if (lane >= d) v1 += u;
      }
      v1 += tot0;
      lh[lane + 1] = v0;
      lh[lane + 65] = v1;
    }
    __syncthreads();
    if (t < 128) lc[t] = lh[t];
    __syncthreads();
#pragma unroll
    for (int j = 0; j < 11; ++j) {
      if (j < nrec) {
        int q = atomicAdd(&lc[rec[j].x >> 17], 1);
        srt[q] = make_uint2(rec[j].x & 0x1FFFFu, rec[j].y);
      }
    }
    __syncthreads();

#pragma unroll 1
    for (int i = wid * 16; i < wid * 16 + 16; ++i) {
      if (i >= nmax) break;
      const int s = lh[i];
      const int e2 = lh[i + 1];
      float a0 = 0.f, a1 = 0.f, a2 = 0.f, a3 = 0.f;
      float a4 = 0.f, a5 = 0.f, a6 = 0.f, a7 = 0.f;
#pragma unroll 1
      for (int p = s; p < e2; p += 8) {
#pragma unroll
        for (int j = 0; j < 4; ++j) {
          int idx = p + j * 2 + h;
          bool ok = idx < e2;
          uint2 r = srt[ok ? idx : s];
          float wgt = ok ? __uint_as_float(r.y) : 0.f;
          uint4 v = *(const uint4*)(xw + (size_t)r.x * DDIM + g0);
          a0 += wgt * bfLO(v.x); a1 += wgt * bfHI(v.x);
          a2 += wgt * bfLO(v.y); a3 += wgt * bfHI(v.y);
          a4 += wgt * bfLO(v.z); a5 += wgt * bfHI(v.z);
          a6 += wgt * bfLO(v.w); a7 += wgt * bfHI(v.w);
        }
      }
      a0 += __shfl_xor(a0, 32); a1 += __shfl_xor(a1, 32);
      a2 += __shfl_xor(a2, 32); a3 += __shfl_xor(a3, 32);
      a4 += __shfl_xor(a4, 32); a5 += __shfl_xor(a5, 32);
      a6 += __shfl_xor(a6, 32); a7 += __shfl_xor(a7, 32);
      float4 o = h ? make_float4(a4 + bv.x, a5 + bv.y, a6 + bv.z, a7 + bv.w)
                   : make_float4(a0 + bv.x, a1 + bv.y, a2 + bv.z, a3 + bv.w);
      *(float4*)(z + (size_t)(nbase + i) * DDIM + c0) = o;
    }
  } else {
    // fallback (data-safety; statistically unreachable): scan all records per node
    const int c4 = lane * 4;
    const float4 bf = *(const float4*)(bias + c4);
#pragma unroll 1
    for (int i = wid * 16; i < wid * 16 + 16; ++i) {
      if (i >= nmax) break;
      float a0 = 0.f, a1 = 0.f, a2 = 0.f, a3 = 0.f;
      for (int p = 0; p < cnt; ++p) {
        uint2 r = bin[beg + p];
        if ((int)(r.x >> 17) == i) {
          float wgt = __uint_as_float(r.y);
          ushort4 v = *(const ushort4*)(xw + (size_t)(r.x & 0x1FFFFu) * DDIM + c4);
          a0 += wgt * bf16_to_f32(v.x);
          a1 += wgt * bf16_to_f32(v.y);
          a2 += wgt * bf16_to_f32(v.z);
          a3 += wgt * bf16_to_f32(v.w);
        }
      }
      *(float4*)(z + (size_t)(nbase + i) * DDIM + c4) =
          make_float4(a0 + bf.x, a1 + bf.y, a2 + bf.z, a3 + bf.w);
    }
  }
}

extern "C" void kernel_launch(void* const* d_in, const int* in_sizes, int n_in,
                              void* d_out, int out_size, void* d_ws, size_t ws_size,
                              hipStream_t stream) {
  const float* x = (const float*)d_in[0];
  const float* w = (const float*)d_in[1];
  const float* bias = (const float*)d_in[2];
  const int* esrc = (const int*)d_in[3];
  const int* edst = (const int*)d_in[4];
  const float* ew = (const float*)d_in[5];
  float* z = (float*)d_out;

  char* ws = (char*)d_ws;
  size_t off = 0;
  unsigned short* xw = (unsigned short*)(ws + off);
  off += (size_t)N_NODES * DDIM * 2;                        // 51.2 MB
  unsigned short* xb = (unsigned short*)(ws + off);
  off += (size_t)N_NODES * DDIM * 2;                        // 51.2 MB
  unsigned short* wt = (unsigned short*)(ws + off);
  off += (size_t)DDIM * DDIM * 2;                           // 128 KB
  int* bcnt = (int*)(ws + off);
  off += (size_t)NB * 16 * 4;                               // 50 KB (line-padded)
  int* boff = (int*)(ws + off);
  off += (((size_t)(NB + 1) * 4) + 255) / 256 * 256;
  int* bcur = (int*)(ws + off);
  off += (size_t)NB * 16 * 4;                               // 50 KB (line-padded)
  uint2* bin = (uint2*)(ws + off);
  off += (size_t)N_EDGES * 8;                               // 25.6 MB

  hipMemsetAsync(bcnt, 0, (size_t)NB * 16 * 4, stream);
  k_bhist<<<512, 256, 0, stream>>>(edst, bcnt);
  k_bscan<<<1, 1024, 0, stream>>>(bcnt, boff, bcur);
  k_bin<<<(N_EDGES + BINBLK - 1) / BINBLK, 256, 0, stream>>>(esrc, edst, ew, bcur, bin);
  k_cvtX<<<(N_NODES * DDIM / 8 + 255) / 256, 256, 0, stream>>>(x, xb);
  k_cvtW<<<(DDIM * DDIM + 255) / 256, 256, 0, stream>>>(w, wt);
  dim3 gg((N_NODES + 127) / 128, DDIM / 64);
  k_gemm<<<gg, 256, 0, stream>>>(xb, wt, xw);
  k_baggr<<<NB, 512, 0, stream>>>(bin, boff, xw, bias, z);
}

// Round 5
// 462.426 us; speedup vs baseline: 2.2707x; 1.0488x over previous
//
#include <hip/hip_runtime.h>
#include <hip/hip_bf16.h>
#include <stdint.h>

#define N_NODES 100000
#define N_EDGES 3200000
#define DDIM 256
#define NB 782        // ceil(100000 / 128) buckets of 128 dst nodes
#define CAP 4800      // LDS sort capacity per bucket (mean 4092, sd 64; 11 sigma + fallback)
#define BINBLK 4096   // edges per k_bin block

typedef __attribute__((ext_vector_type(8))) short short8v;
typedef __attribute__((ext_vector_type(4))) float f32x4;

static __device__ __forceinline__ unsigned short f32_to_bf16_rne(float f) {
  unsigned u = __float_as_uint(f);
  unsigned rounded = u + 0x7FFFu + ((u >> 16) & 1u);
  return (unsigned short)(rounded >> 16);
}

static __device__ __forceinline__ float bf16_to_f32(unsigned short h) {
  return __uint_as_float((unsigned)h << 16);
}

// bf16 pair unpack from packed u32
static __device__ __forceinline__ float bfLO(unsigned v) { return __uint_as_float(v << 16); }
static __device__ __forceinline__ float bfHI(unsigned v) { return __uint_as_float(v & 0xFFFF0000u); }

// ---------------- bucket histogram (LDS-staged) ----------------

__global__ __launch_bounds__(256) void k_bhist(const int* __restrict__ dst,
                                               int* __restrict__ bcnt) {
  __shared__ int h[NB];
  for (int i = threadIdx.x; i < NB; i += 256) h[i] = 0;
  __syncthreads();
  const int stride = gridDim.x * 256;
  for (int e = blockIdx.x * 256 + threadIdx.x; e < N_EDGES; e += stride)
    atomicAdd(&h[dst[e] >> 7], 1);
  __syncthreads();
  for (int i = threadIdx.x; i < NB; i += 256) {
    int v = h[i];
    if (v) atomicAdd(&bcnt[i * 16], v);   // cursors padded: 1 per 64B line
  }
}

// ---------------- bucket offsets scan ----------------

__global__ __launch_bounds__(1024) void k_bscan(const int* __restrict__ bcnt,
                                                int* __restrict__ boff,
                                                int* __restrict__ bcur) {
  __shared__ int part[1024];
  int t = threadIdx.x;
  part[t] = (t < NB) ? bcnt[t * 16] : 0;
  __syncthreads();
  for (int off = 1; off < 1024; off <<= 1) {
    int v = (t >= off) ? part[t - off] : 0;
    __syncthreads();
    part[t] += v;
    __syncthreads();
  }
  if (t < NB) {
    int excl = (t == 0) ? 0 : part[t - 1];
    boff[t] = excl;
    bcur[t * 16] = excl;
  }
  if (t == 0) boff[NB] = N_EDGES;
}

// ---------------- bin edges: block-level LDS binning ----------------

__global__ __launch_bounds__(256) void k_bin(const int* __restrict__ src,
                                             const int* __restrict__ dst,
                                             const float* __restrict__ w,
                                             int* __restrict__ bcur,
                                             uint2* __restrict__ bin) {
  __shared__ int hist[NB];   // counts, then cursors
  const int t = threadIdx.x;
  const int e0 = blockIdx.x * BINBLK;
  int n = N_EDGES - e0;
  if (n > BINBLK) n = BINBLK;
  for (int i = t; i < NB; i += 256) hist[i] = 0;
  __syncthreads();
  int myd[16];
#pragma unroll
  for (int j = 0; j < 16; ++j) {
    int p = j * 256 + t;
    if (p < n) {
      myd[j] = dst[e0 + p];
      atomicAdd(&hist[myd[j] >> 7], 1);
    } else {
      myd[j] = -1;
    }
  }
  __syncthreads();
  for (int i = t; i < NB; i += 256) {
    int h = hist[i];
    hist[i] = h ? atomicAdd(&bcur[i * 16], h) : 0;   // hist becomes cursor
  }
  __syncthreads();
#pragma unroll
  for (int j = 0; j < 16; ++j) {
    int p = j * 256 + t;
    if (p < n) {
      int d = myd[j];
      int q = atomicAdd(&hist[d >> 7], 1);
      bin[q] = make_uint2(((unsigned)(d & 127) << 17) | (unsigned)src[e0 + p],
                          __float_as_uint(w[e0 + p]));
    }
  }
}

// ---------------- Wt[n][k] = W[k][n], bf16 ----------------

__global__ __launch_bounds__(256) void k_cvtW(const float* __restrict__ w,
                                              unsigned short* __restrict__ wt) {
  int i = blockIdx.x * blockDim.x + threadIdx.x;
  int k = i >> 8;
  int n = i & 255;
  wt[(size_t)n * DDIM + k] = f32_to_bf16_rne(w[(size_t)k * DDIM + n]);
}

// ---------------- GEMM: XW = X @ W (bf16 MFMA), fused f32->bf16 A-stage ----
// 512 threads = 8 waves (4M x 2N); tile 128(M) x 256(N=all), BK=64.
// A: reg-stage x f32 -> pack bf16 -> XOR-swizzled ds_write_b128.
// B: global_load_lds linear dest + pre-swizzled global source.

__global__ __launch_bounds__(512, 2) void k_gemm(const float* __restrict__ x,
                                                 const unsigned short* __restrict__ wt,
                                                 unsigned short* __restrict__ xw) {
  __shared__ unsigned short As[128 * 64];   // [m][k] 16 KB
  __shared__ unsigned short Bs[256 * 64];   // [n][k] 32 KB
  const int t = threadIdx.x;
  const int lane = t & 63;
  const int wid = t >> 6;          // 0..7
  const int wr = wid >> 1;         // 0..3  M quadrant (32 rows)
  const int wc = wid & 1;          // 0..1  N half (128 cols)
  const int m0 = blockIdx.x * 128;

  f32x4 acc[2][8] = {};

  // A staging coords: thread -> (row, 16-wide k chunk)
  const int arow = t >> 2;         // 0..127
  const int akb = (t & 3) * 16;    // k offset
  int am = m0 + arow;
  if (am > N_NODES - 1) am = N_NODES - 1;
  // B staging coords
  const int sr = t >> 3;           // 0..63
  const int sc = t & 7;

  const int kg = lane >> 4;
  const int rl = lane & 15;

  for (int kt = 0; kt < 4; ++kt) {
    const int k0 = kt * 64;
    // B: 4 passes of 64 rows, async to LDS
#pragma unroll
    for (int i = 0; i < 4; ++i) {
      int r = i * 64 + sr;
      int cc = sc ^ (r & 7);
      const unsigned short* srcp = wt + (size_t)r * DDIM + k0 + cc * 8;
      __builtin_amdgcn_global_load_lds(
          (const __attribute__((address_space(1))) void*)srcp,
          (__attribute__((address_space(3))) void*)((char*)Bs + i * 8192 + t * 16),
          16, 0, 0);
    }
    // A: load 16 f32, pack to 16 bf16, 2 swizzled b128 writes
    {
      const float* xp = x + (size_t)am * DDIM + k0 + akb;
      float4 f0 = *(const float4*)(xp + 0);
      float4 f1 = *(const float4*)(xp + 4);
      float4 f2 = *(const float4*)(xp + 8);
      float4 f3 = *(const float4*)(xp + 12);
      uint4 p0, p1;
      p0.x = (unsigned)f32_to_bf16_rne(f0.x) | ((unsigned)f32_to_bf16_rne(f0.y) << 16);
      p0.y = (unsigned)f32_to_bf16_rne(f0.z) | ((unsigned)f32_to_bf16_rne(f0.w) << 16);
      p0.z = (unsigned)f32_to_bf16_rne(f1.x) | ((unsigned)f32_to_bf16_rne(f1.y) << 16);
      p0.w = (unsigned)f32_to_bf16_rne(f1.z) | ((unsigned)f32_to_bf16_rne(f1.w) << 16);
      p1.x = (unsigned)f32_to_bf16_rne(f2.x) | ((unsigned)f32_to_bf16_rne(f2.y) << 16);
      p1.y = (unsigned)f32_to_bf16_rne(f2.z) | ((unsigned)f32_to_bf16_rne(f2.w) << 16);
      p1.z = (unsigned)f32_to_bf16_rne(f3.x) | ((unsigned)f32_to_bf16_rne(f3.y) << 16);
      p1.w = (unsigned)f32_to_bf16_rne(f3.z) | ((unsigned)f32_to_bf16_rne(f3.w) << 16);
      int b0 = arow * 128 + akb * 2;
      int swz = (arow & 7) << 4;
      *(uint4*)((char*)As + (b0 ^ swz)) = p0;
      *(uint4*)((char*)As + ((b0 + 16) ^ swz)) = p1;
    }
    __syncthreads();

#pragma unroll
    for (int ks = 0; ks < 2; ++ks) {
      const int colbyte = ks * 64 + kg * 16;
      short8v af[2];
#pragma unroll
      for (int mi = 0; mi < 2; ++mi) {
        int row = wr * 32 + mi * 16 + rl;
        int b = row * 128 + (colbyte ^ ((row & 7) << 4));
        af[mi] = *(const short8v*)((const char*)As + b);
      }
#pragma unroll
      for (int ni = 0; ni < 8; ++ni) {
        int row = wc * 128 + ni * 16 + rl;
        int b = row * 128 + (colbyte ^ ((row & 7) << 4));
        short8v bf = *(const short8v*)((const char*)Bs + b);
        acc[0][ni] = __builtin_amdgcn_mfma_f32_16x16x32_bf16(af[0], bf, acc[0][ni], 0, 0, 0);
        acc[1][ni] = __builtin_amdgcn_mfma_f32_16x16x32_bf16(af[1], bf, acc[1][ni], 0, 0, 0);
      }
    }
    __syncthreads();
  }

  const int rbase = (lane >> 4) * 4;
  const int ncol = lane & 15;
#pragma unroll
  for (int mi = 0; mi < 2; ++mi) {
#pragma unroll
    for (int ni = 0; ni < 8; ++ni) {
      int n = wc * 128 + ni * 16 + ncol;
#pragma unroll
      for (int r = 0; r < 4; ++r) {
        int m = m0 + wr * 32 + mi * 16 + rbase + r;
        if (m < N_NODES)
          xw[(size_t)m * DDIM + n] = f32_to_bf16_rne(acc[mi][ni][r]);
      }
    }
  }
}

// ---------------- bucket sort (LDS) + aggregate ----------------
// one block of 512 per bucket; counting-sort records in LDS, then one wave
// per 16 local nodes aggregates. Edge-pair mode: half-wave h handles edge
// p+h; lane owns 8 channels via 16B loads; cross-half shfl_xor combine.

__global__ __launch_bounds__(512, 8) void k_baggr(const uint2* __restrict__ bin,
                                                  const int* __restrict__ boff,
                                                  const unsigned short* __restrict__ xw,
                                                  const float* __restrict__ bias,
                                                  float* __restrict__ z) {
  __shared__ uint2 srt[CAP];   // 37.5 KB -> ~40 KB block => 4 blocks/CU
  __shared__ int lh[129];
  __shared__ int lc[128];
  const int b = blockIdx.x;
  const int t = threadIdx.x;
  const int beg = boff[b];
  const int cnt = boff[b + 1] - beg;
  const int nbase = b << 7;
  int nmax = N_NODES - nbase;
  if (nmax > 128) nmax = 128;

  if (t < 129) lh[t] = 0;
  __syncthreads();

  const int wid = t >> 6;
  const int lane = t & 63;
  const int h = lane >> 5;       // edge-pair half
  const int l5 = lane & 31;
  const int g0 = l5 * 8;         // gather col (8 ch, 16B)
  const int c0 = g0 + h * 4;     // write col (4 ch)
  const float4 bv = *(const float4*)(bias + c0);

  if (cnt <= CAP) {
    uint2 rec[10];               // ceil(CAP/512) = 10
    int nrec = 0;
#pragma unroll
    for (int j = 0; j < 10; ++j) {
      int p = t + j * 512;
      if (p < cnt) {
        rec[j] = bin[beg + p];
        atomicAdd(&lh[(rec[j].x >> 17) + 1], 1);
        nrec = j + 1;
      }
    }
    __syncthreads();
    if (wid == 0) {  // wave-parallel inclusive scan of lh[1..128]
      int v0 = lh[lane + 1];
      int v1 = lh[lane + 65];
#pragma unroll
      for (int d = 1; d < 64; d <<= 1) {
        int u = __shfl_up(v0, d);
        if (lane >= d) v0 += u;
      }
      int tot0 = __shfl(v0, 63);
#pragma unroll
      for (int d = 1; d < 64; d <<= 1) {
        int u = __shfl_up(v1, d);
        if (lane >= d) v1 += u;
      }
      v1 += tot0;
      lh[lane + 1] = v0;
      lh[lane + 65] = v1;
    }
    __syncthreads();
    if (t < 128) lc[t] = lh[t];
    __syncthreads();
#pragma unroll
    for (int j = 0; j < 10; ++j) {
      if (j < nrec) {
        int q = atomicAdd(&lc[rec[j].x >> 17], 1);
        srt[q] = make_uint2(rec[j].x & 0x1FFFFu, rec[j].y);
      }
    }
    __syncthreads();

#pragma unroll 1
    for (int i = wid * 16; i < wid * 16 + 16; ++i) {
      if (i >= nmax) break;
      const int s = lh[i];
      const int e2 = lh[i + 1];
      float a0 = 0.f, a1 = 0.f, a2 = 0.f, a3 = 0.f;
      float a4 = 0.f, a5 = 0.f, a6 = 0.f, a7 = 0.f;
#pragma unroll 1
      for (int p = s; p < e2; p += 8) {
#pragma unroll
        for (int j = 0; j < 4; ++j) {
          int idx = p + j * 2 + h;
          bool ok = idx < e2;
          uint2 r = srt[ok ? idx : s];
          float wgt = ok ? __uint_as_float(r.y) : 0.f;
          uint4 v = *(const uint4*)(xw + (size_t)r.x * DDIM + g0);
          a0 += wgt * bfLO(v.x); a1 += wgt * bfHI(v.x);
          a2 += wgt * bfLO(v.y); a3 += wgt * bfHI(v.y);
          a4 += wgt * bfLO(v.z); a5 += wgt * bfHI(v.z);
          a6 += wgt * bfLO(v.w); a7 += wgt * bfHI(v.w);
        }
      }
      a0 += __shfl_xor(a0, 32); a1 += __shfl_xor(a1, 32);
      a2 += __shfl_xor(a2, 32); a3 += __shfl_xor(a3, 32);
      a4 += __shfl_xor(a4, 32); a5 += __shfl_xor(a5, 32);
      a6 += __shfl_xor(a6, 32); a7 += __shfl_xor(a7, 32);
      float4 o = h ? make_float4(a4 + bv.x, a5 + bv.y, a6 + bv.z, a7 + bv.w)
                   : make_float4(a0 + bv.x, a1 + bv.y, a2 + bv.z, a3 + bv.w);
      *(float4*)(z + (size_t)(nbase + i) * DDIM + c0) = o;
    }
  } else {
    // fallback (data-safety; statistically unreachable): scan all records per node
    const int c4 = lane * 4;
    const float4 bf = *(const float4*)(bias + c4);
#pragma unroll 1
    for (int i = wid * 16; i < wid * 16 + 16; ++i) {
      if (i >= nmax) break;
      float a0 = 0.f, a1 = 0.f, a2 = 0.f, a3 = 0.f;
      for (int p = 0; p < cnt; ++p) {
        uint2 r = bin[beg + p];
        if ((int)(r.x >> 17) == i) {
          float wgt = __uint_as_float(r.y);
          ushort4 v = *(const ushort4*)(xw + (size_t)(r.x & 0x1FFFFu) * DDIM + c4);
          a0 += wgt * bf16_to_f32(v.x);
          a1 += wgt * bf16_to_f32(v.y);
          a2 += wgt * bf16_to_f32(v.z);
          a3 += wgt * bf16_to_f32(v.w);
        }
      }
      *(float4*)(z + (size_t)(nbase + i) * DDIM + c4) =
          make_float4(a0 + bf.x, a1 + bf.y, a2 + bf.z, a3 + bf.w);
    }
  }
}

extern "C" void kernel_launch(void* const* d_in, const int* in_sizes, int n_in,
                              void* d_out, int out_size, void* d_ws, size_t ws_size,
                              hipStream_t stream) {
  const float* x = (const float*)d_in[0];
  const float* w = (const float*)d_in[1];
  const float* bias = (const float*)d_in[2];
  const int* esrc = (const int*)d_in[3];
  const int* edst = (const int*)d_in[4];
  const float* ew = (const float*)d_in[5];
  float* z = (float*)d_out;

  char* ws = (char*)d_ws;
  size_t off = 0;
  unsigned short* xw = (unsigned short*)(ws + off);
  off += (size_t)N_NODES * DDIM * 2;                        // 51.2 MB
  unsigned short* wt = (unsigned short*)(ws + off);
  off += (size_t)DDIM * DDIM * 2;                           // 128 KB
  int* bcnt = (int*)(ws + off);
  off += (size_t)NB * 16 * 4;                               // 50 KB (line-padded)
  int* boff = (int*)(ws + off);
  off += (((size_t)(NB + 1) * 4) + 255) / 256 * 256;
  int* bcur = (int*)(ws + off);
  off += (size_t)NB * 16 * 4;                               // 50 KB (line-padded)
  uint2* bin = (uint2*)(ws + off);
  off += (size_t)N_EDGES * 8;                               // 25.6 MB

  hipMemsetAsync(bcnt, 0, (size_t)NB * 16 * 4, stream);
  k_bhist<<<512, 256, 0, stream>>>(edst, bcnt);
  k_bscan<<<1, 1024, 0, stream>>>(bcnt, boff, bcur);
  k_bin<<<(N_EDGES + BINBLK - 1) / BINBLK, 256, 0, stream>>>(esrc, edst, ew, bcur, bin);
  k_cvtW<<<(DDIM * DDIM + 255) / 256, 256, 0, stream>>>(w, wt);
  k_gemm<<<NB, 512, 0, stream>>>(x, wt, xw);
  k_baggr<<<NB, 512, 0, stream>>>(bin, boff, xw, bias, z);
}

// Round 6
// 427.353 us; speedup vs baseline: 2.4570x; 1.0821x over previous
//
#include <hip/hip_runtime.h>
#include <hip/hip_bf16.h>
#include <stdint.h>

#define N_NODES 100000
#define N_EDGES 3200000
#define DDIM 256
#define NB 782        // ceil(100000 / 128) buckets of 128 dst nodes
#define CAP 4800      // per-bucket slot capacity (mean 4092, sd 64; 11 sigma)
#define BINBLK 4096   // edges per k_bin block
#define OCAP 65536    // overflow list capacity (statistically unreachable)

typedef __attribute__((ext_vector_type(8))) short short8v;
typedef __attribute__((ext_vector_type(4))) float f32x4;

static __device__ __forceinline__ unsigned short f32_to_bf16_rne(float f) {
  unsigned u = __float_as_uint(f);
  unsigned rounded = u + 0x7FFFu + ((u >> 16) & 1u);
  return (unsigned short)(rounded >> 16);
}

static __device__ __forceinline__ float bf16_to_f32(unsigned short h) {
  return __uint_as_float((unsigned)h << 16);
}

static __device__ __forceinline__ float bfLO(unsigned v) { return __uint_as_float(v << 16); }
static __device__ __forceinline__ float bfHI(unsigned v) { return __uint_as_float(v & 0xFFFF0000u); }

// ---------------- bin edges into fixed-stride bucket regions ----------------
// block-level LDS binning: 1 global atomic per (block,bucket).

__global__ __launch_bounds__(256) void k_bin(const int* __restrict__ src,
                                             const int* __restrict__ dst,
                                             const float* __restrict__ w,
                                             int* __restrict__ bcur,
                                             uint2* __restrict__ bin,
                                             uint4* __restrict__ ofl,
                                             int* __restrict__ oflcnt) {
  __shared__ int hist[NB];   // counts, then cursors
  const int t = threadIdx.x;
  const int e0 = blockIdx.x * BINBLK;
  int n = N_EDGES - e0;
  if (n > BINBLK) n = BINBLK;
  for (int i = t; i < NB; i += 256) hist[i] = 0;
  __syncthreads();
  int myd[16];
#pragma unroll
  for (int j = 0; j < 16; ++j) {
    int p = j * 256 + t;
    if (p < n) {
      myd[j] = dst[e0 + p];
      atomicAdd(&hist[myd[j] >> 7], 1);
    } else {
      myd[j] = -1;
    }
  }
  __syncthreads();
  for (int i = t; i < NB; i += 256) {
    int h = hist[i];
    hist[i] = h ? atomicAdd(&bcur[i * 16], h) : 0;   // hist becomes cursor (base in bucket)
  }
  __syncthreads();
#pragma unroll
  for (int j = 0; j < 16; ++j) {
    int p = j * 256 + t;
    if (p < n) {
      int d = myd[j];
      int bkt = d >> 7;
      int q = atomicAdd(&hist[bkt], 1);
      if (q < CAP) {
        bin[(size_t)bkt * CAP + q] =
            make_uint2(((unsigned)(d & 127) << 17) | (unsigned)src[e0 + p],
                       __float_as_uint(w[e0 + p]));
      } else {
        int op = atomicAdd(oflcnt, 1);
        if (op < OCAP)
          ofl[op] = make_uint4((unsigned)d, (unsigned)src[e0 + p],
                               __float_as_uint(w[e0 + p]), 0u);
      }
    }
  }
}

// ---------------- Wt[n][k] = W[k][n], bf16 ----------------

__global__ __launch_bounds__(256) void k_cvtW(const float* __restrict__ w,
                                              unsigned short* __restrict__ wt) {
  int i = blockIdx.x * blockDim.x + threadIdx.x;
  int k = i >> 8;
  int n = i & 255;
  wt[(size_t)n * DDIM + k] = f32_to_bf16_rne(w[(size_t)k * DDIM + n]);
}

// ---------------- GEMM: XW = X @ W (bf16 MFMA), fused f32->bf16 A-stage ----

__global__ __launch_bounds__(512, 2) void k_gemm(const float* __restrict__ x,
                                                 const unsigned short* __restrict__ wt,
                                                 unsigned short* __restrict__ xw) {
  __shared__ unsigned short As[128 * 64];   // [m][k] 16 KB
  __shared__ unsigned short Bs[256 * 64];   // [n][k] 32 KB
  const int t = threadIdx.x;
  const int lane = t & 63;
  const int wid = t >> 6;          // 0..7
  const int wr = wid >> 1;         // 0..3  M quadrant (32 rows)
  const int wc = wid & 1;          // 0..1  N half (128 cols)
  const int m0 = blockIdx.x * 128;

  f32x4 acc[2][8] = {};

  const int arow = t >> 2;         // 0..127
  const int akb = (t & 3) * 16;    // k offset
  int am = m0 + arow;
  if (am > N_NODES - 1) am = N_NODES - 1;
  const int sr = t >> 3;           // 0..63
  const int sc = t & 7;

  const int kg = lane >> 4;
  const int rl = lane & 15;

  for (int kt = 0; kt < 4; ++kt) {
    const int k0 = kt * 64;
#pragma unroll
    for (int i = 0; i < 4; ++i) {
      int r = i * 64 + sr;
      int cc = sc ^ (r & 7);
      const unsigned short* srcp = wt + (size_t)r * DDIM + k0 + cc * 8;
      __builtin_amdgcn_global_load_lds(
          (const __attribute__((address_space(1))) void*)srcp,
          (__attribute__((address_space(3))) void*)((char*)Bs + i * 8192 + t * 16),
          16, 0, 0);
    }
    {
      const float* xp = x + (size_t)am * DDIM + k0 + akb;
      float4 f0 = *(const float4*)(xp + 0);
      float4 f1 = *(const float4*)(xp + 4);
      float4 f2 = *(const float4*)(xp + 8);
      float4 f3 = *(const float4*)(xp + 12);
      uint4 p0, p1;
      p0.x = (unsigned)f32_to_bf16_rne(f0.x) | ((unsigned)f32_to_bf16_rne(f0.y) << 16);
      p0.y = (unsigned)f32_to_bf16_rne(f0.z) | ((unsigned)f32_to_bf16_rne(f0.w) << 16);
      p0.z = (unsigned)f32_to_bf16_rne(f1.x) | ((unsigned)f32_to_bf16_rne(f1.y) << 16);
      p0.w = (unsigned)f32_to_bf16_rne(f1.z) | ((unsigned)f32_to_bf16_rne(f1.w) << 16);
      p1.x = (unsigned)f32_to_bf16_rne(f2.x) | ((unsigned)f32_to_bf16_rne(f2.y) << 16);
      p1.y = (unsigned)f32_to_bf16_rne(f2.z) | ((unsigned)f32_to_bf16_rne(f2.w) << 16);
      p1.z = (unsigned)f32_to_bf16_rne(f3.x) | ((unsigned)f32_to_bf16_rne(f3.y) << 16);
      p1.w = (unsigned)f32_to_bf16_rne(f3.z) | ((unsigned)f32_to_bf16_rne(f3.w) << 16);
      int b0 = arow * 128 + akb * 2;
      int swz = (arow & 7) << 4;
      *(uint4*)((char*)As + (b0 ^ swz)) = p0;
      *(uint4*)((char*)As + ((b0 + 16) ^ swz)) = p1;
    }
    __syncthreads();

#pragma unroll
    for (int ks = 0; ks < 2; ++ks) {
      const int colbyte = ks * 64 + kg * 16;
      short8v af[2];
#pragma unroll
      for (int mi = 0; mi < 2; ++mi) {
        int row = wr * 32 + mi * 16 + rl;
        int b = row * 128 + (colbyte ^ ((row & 7) << 4));
        af[mi] = *(const short8v*)((const char*)As + b);
      }
#pragma unroll
      for (int ni = 0; ni < 8; ++ni) {
        int row = wc * 128 + ni * 16 + rl;
        int b = row * 128 + (colbyte ^ ((row & 7) << 4));
        short8v bf = *(const short8v*)((const char*)Bs + b);
        acc[0][ni] = __builtin_amdgcn_mfma_f32_16x16x32_bf16(af[0], bf, acc[0][ni], 0, 0, 0);
        acc[1][ni] = __builtin_amdgcn_mfma_f32_16x16x32_bf16(af[1], bf, acc[1][ni], 0, 0, 0);
      }
    }
    __syncthreads();
  }

  const int rbase = (lane >> 4) * 4;
  const int ncol = lane & 15;
#pragma unroll
  for (int mi = 0; mi < 2; ++mi) {
#pragma unroll
    for (int ni = 0; ni < 8; ++ni) {
      int n = wc * 128 + ni * 16 + ncol;
#pragma unroll
      for (int r = 0; r < 4; ++r) {
        int m = m0 + wr * 32 + mi * 16 + rbase + r;
        if (m < N_NODES)
          xw[(size_t)m * DDIM + n] = f32_to_bf16_rne(acc[mi][ni][r]);
      }
    }
  }
}

// ---------------- bucket sort (LDS) + aggregate, channel-split ----------------
// one block of 512 per bucket; counting-sort records in LDS. Channel pass cb
// covers 128 channels: 16 lanes per edge (16B each), 4 edges per wave-instr,
// 4-deep explicit batching (16 edges/iter). Cross-group shfl_xor reduce.

__global__ __launch_bounds__(512, 8) void k_baggr(const uint2* __restrict__ bin,
                                                  const int* __restrict__ bcur,
                                                  const unsigned short* __restrict__ xw,
                                                  const float* __restrict__ bias,
                                                  float* __restrict__ z,
                                                  int cb) {
  __shared__ uint2 srt[CAP];   // 37.5 KB
  __shared__ int lh[129];
  __shared__ int lc[128];
  const int b = blockIdx.x;
  const int t = threadIdx.x;
  int cnt = bcur[b * 16];
  if (cnt > CAP) cnt = CAP;
  const int nbase = b << 7;
  int nmax = N_NODES - nbase;
  if (nmax > 128) nmax = 128;

  if (t < 129) lh[t] = 0;
  __syncthreads();

  const int wid = t >> 6;
  const int lane = t & 63;
  const int g = lane >> 4;       // edge group 0..3
  const int l15 = lane & 15;
  const int gcol = cb + l15 * 8; // 8 channels, 16B
  const uint2* mybin = bin + (size_t)b * CAP;

  uint2 rec[10];                 // ceil(CAP/512) = 10
  int nrec = 0;
#pragma unroll
  for (int j = 0; j < 10; ++j) {
    int p = t + j * 512;
    if (p < cnt) {
      rec[j] = mybin[p];
      atomicAdd(&lh[(rec[j].x >> 17) + 1], 1);
      nrec = j + 1;
    }
  }
  __syncthreads();
  if (wid == 0) {  // wave-parallel inclusive scan of lh[1..128]
    int v0 = lh[lane + 1];
    int v1 = lh[lane + 65];
#pragma unroll
    for (int d = 1; d < 64; d <<= 1) {
      int u = __shfl_up(v0, d);
      if (lane >= d) v0 += u;
    }
    int tot0 = __shfl(v0, 63);
#pragma unroll
    for (int d = 1; d < 64; d <<= 1) {
      int u = __shfl_up(v1, d);
      if (lane >= d) v1 += u;
    }
    v1 += tot0;
    lh[lane + 1] = v0;
    lh[lane + 65] = v1;
  }
  __syncthreads();
  if (t < 128) lc[t] = lh[t];
  __syncthreads();
#pragma unroll
  for (int j = 0; j < 10; ++j) {
    if (j < nrec) {
      int q = atomicAdd(&lc[rec[j].x >> 17], 1);
      srt[q] = make_uint2(rec[j].x & 0x1FFFFu, rec[j].y);
    }
  }
  __syncthreads();

#pragma unroll 1
  for (int i = wid * 16; i < wid * 16 + 16; ++i) {
    if (i >= nmax) break;
    const int s = lh[i];
    const int e2 = lh[i + 1];
    float a0 = 0.f, a1 = 0.f, a2 = 0.f, a3 = 0.f;
    float a4 = 0.f, a5 = 0.f, a6 = 0.f, a7 = 0.f;
#pragma unroll 1
    for (int p = s; p < e2; p += 16) {
      unsigned sx0, sx1, sx2, sx3;
      float w0, w1, w2, w3;
      {
        int i0 = p + 0 * 4 + g; bool k0 = i0 < e2; uint2 r = srt[k0 ? i0 : s];
        sx0 = r.x; w0 = k0 ? __uint_as_float(r.y) : 0.f;
      }
      {
        int i1 = p + 1 * 4 + g; bool k1 = i1 < e2; uint2 r = srt[k1 ? i1 : s];
        sx1 = r.x; w1 = k1 ? __uint_as_float(r.y) : 0.f;
      }
      {
        int i2 = p + 2 * 4 + g; bool k2 = i2 < e2; uint2 r = srt[k2 ? i2 : s];
        sx2 = r.x; w2 = k2 ? __uint_as_float(r.y) : 0.f;
      }
      {
        int i3 = p + 3 * 4 + g; bool k3 = i3 < e2; uint2 r = srt[k3 ? i3 : s];
        sx3 = r.x; w3 = k3 ? __uint_as_float(r.y) : 0.f;
      }
      uint4 v0 = *(const uint4*)(xw + (size_t)sx0 * DDIM + gcol);
      uint4 v1 = *(const uint4*)(xw + (size_t)sx1 * DDIM + gcol);
      uint4 v2 = *(const uint4*)(xw + (size_t)sx2 * DDIM + gcol);
      uint4 v3 = *(const uint4*)(xw + (size_t)sx3 * DDIM + gcol);
      a0 += w0 * bfLO(v0.x); a1 += w0 * bfHI(v0.x);
      a2 += w0 * bfLO(v0.y); a3 += w0 * bfHI(v0.y);
      a4 += w0 * bfLO(v0.z); a5 += w0 * bfHI(v0.z);
      a6 += w0 * bfLO(v0.w); a7 += w0 * bfHI(v0.w);
      a0 += w1 * bfLO(v1.x); a1 += w1 * bfHI(v1.x);
      a2 += w1 * bfLO(v1.y); a3 += w1 * bfHI(v1.y);
      a4 += w1 * bfLO(v1.z); a5 += w1 * bfHI(v1.z);
      a6 += w1 * bfLO(v1.w); a7 += w1 * bfHI(v1.w);
      a0 += w2 * bfLO(v2.x); a1 += w2 * bfHI(v2.x);
      a2 += w2 * bfLO(v2.y); a3 += w2 * bfHI(v2.y);
      a4 += w2 * bfLO(v2.z); a5 += w2 * bfHI(v2.z);
      a6 += w2 * bfLO(v2.w); a7 += w2 * bfHI(v2.w);
      a0 += w3 * bfLO(v3.x); a1 += w3 * bfHI(v3.x);
      a2 += w3 * bfLO(v3.y); a3 += w3 * bfHI(v3.y);
      a4 += w3 * bfLO(v3.z); a5 += w3 * bfHI(v3.z);
      a6 += w3 * bfLO(v3.w); a7 += w3 * bfHI(v3.w);
    }
    a0 += __shfl_xor(a0, 16); a0 += __shfl_xor(a0, 32);
    a1 += __shfl_xor(a1, 16); a1 += __shfl_xor(a1, 32);
    a2 += __shfl_xor(a2, 16); a2 += __shfl_xor(a2, 32);
    a3 += __shfl_xor(a3, 16); a3 += __shfl_xor(a3, 32);
    a4 += __shfl_xor(a4, 16); a4 += __shfl_xor(a4, 32);
    a5 += __shfl_xor(a5, 16); a5 += __shfl_xor(a5, 32);
    a6 += __shfl_xor(a6, 16); a6 += __shfl_xor(a6, 32);
    a7 += __shfl_xor(a7, 16); a7 += __shfl_xor(a7, 32);
    if (g < 2) {
      const float4 bv = *(const float4*)(bias + gcol + (g ? 4 : 0));
      float4 o = g ? make_float4(a4 + bv.x, a5 + bv.y, a6 + bv.z, a7 + bv.w)
                   : make_float4(a0 + bv.x, a1 + bv.y, a2 + bv.z, a3 + bv.w);
      *(float4*)(z + (size_t)(nbase + i) * DDIM + gcol + (g ? 4 : 0)) = o;
    }
  }
}

// ---------------- overflow fixup (normally empty) ----------------

__global__ __launch_bounds__(256) void k_ofl(const uint4* __restrict__ ofl,
                                             const int* __restrict__ oflcnt,
                                             const unsigned short* __restrict__ xw,
                                             float* __restrict__ z) {
  int n = oflcnt[0];
  if (n > OCAP) n = OCAP;
  for (int r = blockIdx.x; r < n; r += gridDim.x) {
    uint4 rec = ofl[r];
    float wgt = __uint_as_float(rec.z);
    int c = threadIdx.x;
    float v = bf16_to_f32(xw[(size_t)rec.y * DDIM + c]);
    atomicAdd(&z[(size_t)rec.x * DDIM + c], wgt * v);
  }
}

extern "C" void kernel_launch(void* const* d_in, const int* in_sizes, int n_in,
                              void* d_out, int out_size, void* d_ws, size_t ws_size,
                              hipStream_t stream) {
  const float* x = (const float*)d_in[0];
  const float* w = (const float*)d_in[1];
  const float* bias = (const float*)d_in[2];
  const int* esrc = (const int*)d_in[3];
  const int* edst = (const int*)d_in[4];
  const float* ew = (const float*)d_in[5];
  float* z = (float*)d_out;

  char* ws = (char*)d_ws;
  size_t off = 0;
  unsigned short* xw = (unsigned short*)(ws + off);
  off += (size_t)N_NODES * DDIM * 2;                        // 51.2 MB
  unsigned short* wt = (unsigned short*)(ws + off);
  off += (size_t)DDIM * DDIM * 2;                           // 128 KB
  int* bcur = (int*)(ws + off);
  off += (size_t)NB * 16 * 4;                               // 50 KB (line-padded cursors)
  int* oflcnt = (int*)(ws + off);
  off += 256;
  uint4* ofl = (uint4*)(ws + off);
  off += (size_t)OCAP * 16;                                 // 1 MB
  uint2* bin = (uint2*)(ws + off);
  off += (size_t)NB * CAP * 8;                              // 30 MB
  // total ~82.5 MB

  hipMemsetAsync(bcur, 0, (size_t)NB * 16 * 4 + 256, stream);  // bcur + oflcnt
  k_bin<<<(N_EDGES + BINBLK - 1) / BINBLK, 256, 0, stream>>>(esrc, edst, ew, bcur, bin,
                                                             ofl, oflcnt);
  k_cvtW<<<(DDIM * DDIM + 255) / 256, 256, 0, stream>>>(w, wt);
  k_gemm<<<(N_NODES + 127) / 128, 512, 0, stream>>>(x, wt, xw);
  k_baggr<<<NB, 512, 0, stream>>>(bin, bcur, xw, bias, z, 0);
  k_baggr<<<NB, 512, 0, stream>>>(bin, bcur, xw, bias, z, 128);
  k_ofl<<<64, 256, 0, stream>>>(ofl, oflcnt, xw, z);
}

// Round 7
// 407.007 us; speedup vs baseline: 2.5798x; 1.0500x over previous
//
#include <hip/hip_runtime.h>
#include <hip/hip_bf16.h>
#include <stdint.h>

#define N_NODES 100000
#define N_EDGES 3200000
#define DDIM 256
#define NB 782        // ceil(100000 / 128) buckets of 128 dst nodes
#define CAP 4800      // per-bucket slot capacity (mean 4092, sd 64; 11 sigma)
#define BINBLK 4096   // edges per k_bin block
#define OCAP 65536    // overflow list capacity (statistically unreachable)

typedef __attribute__((ext_vector_type(8))) short short8v;
typedef __attribute__((ext_vector_type(4))) float f32x4;

static __device__ __forceinline__ unsigned short f32_to_bf16_rne(float f) {
  unsigned u = __float_as_uint(f);
  unsigned rounded = u + 0x7FFFu + ((u >> 16) & 1u);
  return (unsigned short)(rounded >> 16);
}

static __device__ __forceinline__ float bf16_to_f32(unsigned short h) {
  return __uint_as_float((unsigned)h << 16);
}

static __device__ __forceinline__ float bfLO(unsigned v) { return __uint_as_float(v << 16); }
static __device__ __forceinline__ float bfHI(unsigned v) { return __uint_as_float(v & 0xFFFF0000u); }

// ---------------- bin edges into fixed-stride bucket regions ----------------
// block-level LDS binning: 1 global atomic per (block,bucket).

__global__ __launch_bounds__(256) void k_bin(const int* __restrict__ src,
                                             const int* __restrict__ dst,
                                             const float* __restrict__ w,
                                             int* __restrict__ bcur,
                                             uint2* __restrict__ bin,
                                             uint4* __restrict__ ofl,
                                             int* __restrict__ oflcnt) {
  __shared__ int hist[NB];   // counts, then cursors
  const int t = threadIdx.x;
  const int e0 = blockIdx.x * BINBLK;
  int n = N_EDGES - e0;
  if (n > BINBLK) n = BINBLK;
  for (int i = t; i < NB; i += 256) hist[i] = 0;
  __syncthreads();
  int myd[16];
#pragma unroll
  for (int j = 0; j < 16; ++j) {
    int p = j * 256 + t;
    if (p < n) {
      myd[j] = dst[e0 + p];
      atomicAdd(&hist[myd[j] >> 7], 1);
    } else {
      myd[j] = -1;
    }
  }
  __syncthreads();
  for (int i = t; i < NB; i += 256) {
    int h = hist[i];
    hist[i] = h ? atomicAdd(&bcur[i * 16], h) : 0;   // hist becomes cursor (base in bucket)
  }
  __syncthreads();
#pragma unroll
  for (int j = 0; j < 16; ++j) {
    int p = j * 256 + t;
    if (p < n) {
      int d = myd[j];
      int bkt = d >> 7;
      int q = atomicAdd(&hist[bkt], 1);
      if (q < CAP) {
        bin[(size_t)bkt * CAP + q] =
            make_uint2(((unsigned)(d & 127) << 17) | (unsigned)src[e0 + p],
                       __float_as_uint(w[e0 + p]));
      } else {
        int op = atomicAdd(oflcnt, 1);
        if (op < OCAP)
          ofl[op] = make_uint4((unsigned)d, (unsigned)src[e0 + p],
                               __float_as_uint(w[e0 + p]), 0u);
      }
    }
  }
}

// ---------------- Wt[n][k] = W[k][n], bf16 ----------------

__global__ __launch_bounds__(256) void k_cvtW(const float* __restrict__ w,
                                              unsigned short* __restrict__ wt) {
  int i = blockIdx.x * blockDim.x + threadIdx.x;
  int k = i >> 8;
  int n = i & 255;
  wt[(size_t)n * DDIM + k] = f32_to_bf16_rne(w[(size_t)k * DDIM + n]);
}

// ---------------- GEMM: XW = X @ W (bf16 MFMA), fused f32->bf16 A-stage ----

__global__ __launch_bounds__(512, 2) void k_gemm(const float* __restrict__ x,
                                                 const unsigned short* __restrict__ wt,
                                                 unsigned short* __restrict__ xw) {
  __shared__ unsigned short As[128 * 64];   // [m][k] 16 KB
  __shared__ unsigned short Bs[256 * 64];   // [n][k] 32 KB
  const int t = threadIdx.x;
  const int lane = t & 63;
  const int wid = t >> 6;          // 0..7
  const int wr = wid >> 1;         // 0..3  M quadrant (32 rows)
  const int wc = wid & 1;          // 0..1  N half (128 cols)
  const int m0 = blockIdx.x * 128;

  f32x4 acc[2][8] = {};

  const int arow = t >> 2;         // 0..127
  const int akb = (t & 3) * 16;    // k offset
  int am = m0 + arow;
  if (am > N_NODES - 1) am = N_NODES - 1;
  const int sr = t >> 3;           // 0..63
  const int sc = t & 7;

  const int kg = lane >> 4;
  const int rl = lane & 15;

  for (int kt = 0; kt < 4; ++kt) {
    const int k0 = kt * 64;
#pragma unroll
    for (int i = 0; i < 4; ++i) {
      int r = i * 64 + sr;
      int cc = sc ^ (r & 7);
      const unsigned short* srcp = wt + (size_t)r * DDIM + k0 + cc * 8;
      __builtin_amdgcn_global_load_lds(
          (const __attribute__((address_space(1))) void*)srcp,
          (__attribute__((address_space(3))) void*)((char*)Bs + i * 8192 + t * 16),
          16, 0, 0);
    }
    {
      const float* xp = x + (size_t)am * DDIM + k0 + akb;
      float4 f0 = *(const float4*)(xp + 0);
      float4 f1 = *(const float4*)(xp + 4);
      float4 f2 = *(const float4*)(xp + 8);
      float4 f3 = *(const float4*)(xp + 12);
      uint4 p0, p1;
      p0.x = (unsigned)f32_to_bf16_rne(f0.x) | ((unsigned)f32_to_bf16_rne(f0.y) << 16);
      p0.y = (unsigned)f32_to_bf16_rne(f0.z) | ((unsigned)f32_to_bf16_rne(f0.w) << 16);
      p0.z = (unsigned)f32_to_bf16_rne(f1.x) | ((unsigned)f32_to_bf16_rne(f1.y) << 16);
      p0.w = (unsigned)f32_to_bf16_rne(f1.z) | ((unsigned)f32_to_bf16_rne(f1.w) << 16);
      p1.x = (unsigned)f32_to_bf16_rne(f2.x) | ((unsigned)f32_to_bf16_rne(f2.y) << 16);
      p1.y = (unsigned)f32_to_bf16_rne(f2.z) | ((unsigned)f32_to_bf16_rne(f2.w) << 16);
      p1.z = (unsigned)f32_to_bf16_rne(f3.x) | ((unsigned)f32_to_bf16_rne(f3.y) << 16);
      p1.w = (unsigned)f32_to_bf16_rne(f3.z) | ((unsigned)f32_to_bf16_rne(f3.w) << 16);
      int b0 = arow * 128 + akb * 2;
      int swz = (arow & 7) << 4;
      *(uint4*)((char*)As + (b0 ^ swz)) = p0;
      *(uint4*)((char*)As + ((b0 + 16) ^ swz)) = p1;
    }
    __syncthreads();

#pragma unroll
    for (int ks = 0; ks < 2; ++ks) {
      const int colbyte = ks * 64 + kg * 16;
      short8v af[2];
#pragma unroll
      for (int mi = 0; mi < 2; ++mi) {
        int row = wr * 32 + mi * 16 + rl;
        int b = row * 128 + (colbyte ^ ((row & 7) << 4));
        af[mi] = *(const short8v*)((const char*)As + b);
      }
#pragma unroll
      for (int ni = 0; ni < 8; ++ni) {
        int row = wc * 128 + ni * 16 + rl;
        int b = row * 128 + (colbyte ^ ((row & 7) << 4));
        short8v bf = *(const short8v*)((const char*)Bs + b);
        acc[0][ni] = __builtin_amdgcn_mfma_f32_16x16x32_bf16(af[0], bf, acc[0][ni], 0, 0, 0);
        acc[1][ni] = __builtin_amdgcn_mfma_f32_16x16x32_bf16(af[1], bf, acc[1][ni], 0, 0, 0);
      }
    }
    __syncthreads();
  }

  const int rbase = (lane >> 4) * 4;
  const int ncol = lane & 15;
#pragma unroll
  for (int mi = 0; mi < 2; ++mi) {
#pragma unroll
    for (int ni = 0; ni < 8; ++ni) {
      int n = wc * 128 + ni * 16 + ncol;
#pragma unroll
      for (int r = 0; r < 4; ++r) {
        int m = m0 + wr * 32 + mi * 16 + rbase + r;
        if (m < N_NODES)
          xw[(size_t)m * DDIM + n] = f32_to_bf16_rne(acc[mi][ni][r]);
      }
    }
  }
}

// ---------------- bucket sort (LDS) + aggregate, channel-split ----------------
// grid (NB, 2): blockIdx.x = bucket, blockIdx.y = channel half (128 ch).
// one block of 512; counting-sort records in LDS. 16 lanes per edge (16B
// each), 4 edges per wave-instr, 4-deep batching. Cross-group shfl reduce.

__global__ __launch_bounds__(512, 8) void k_baggr(const uint2* __restrict__ bin,
                                                  const int* __restrict__ bcur,
                                                  const unsigned short* __restrict__ xw,
                                                  const float* __restrict__ bias,
                                                  float* __restrict__ z) {
  __shared__ uint2 srt[CAP];   // 37.5 KB
  __shared__ int lh[129];
  __shared__ int lc[128];
  const int b = blockIdx.x;
  const int cb = blockIdx.y * 128;
  const int t = threadIdx.x;
  int cnt = bcur[b * 16];
  if (cnt > CAP) cnt = CAP;
  const int nbase = b << 7;
  int nmax = N_NODES - nbase;
  if (nmax > 128) nmax = 128;

  if (t < 129) lh[t] = 0;
  __syncthreads();

  const int wid = t >> 6;
  const int lane = t & 63;
  const int g = lane >> 4;       // edge group 0..3
  const int l15 = lane & 15;
  const int gcol = cb + l15 * 8; // 8 channels, 16B
  const uint2* mybin = bin + (size_t)b * CAP;

  uint2 rec[10];                 // ceil(CAP/512) = 10
  int nrec = 0;
#pragma unroll
  for (int j = 0; j < 10; ++j) {
    int p = t + j * 512;
    if (p < cnt) {
      rec[j] = mybin[p];
      atomicAdd(&lh[(rec[j].x >> 17) + 1], 1);
      nrec = j + 1;
    }
  }
  __syncthreads();
  if (wid == 0) {  // wave-parallel inclusive scan of lh[1..128]
    int v0 = lh[lane + 1];
    int v1 = lh[lane + 65];
#pragma unroll
    for (int d = 1; d < 64; d <<= 1) {
      int u = __shfl_up(v0, d);
      if (lane >= d) v0 += u;
    }
    int tot0 = __shfl(v0, 63);
#pragma unroll
    for (int d = 1; d < 64; d <<= 1) {
      int u = __shfl_up(v1, d);
      if (lane >= d) v1 += u;
    }
    v1 += tot0;
    lh[lane + 1] = v0;
    lh[lane + 65] = v1;
  }
  __syncthreads();
  if (t < 128) lc[t] = lh[t];
  __syncthreads();
#pragma unroll
  for (int j = 0; j < 10; ++j) {
    if (j < nrec) {
      int q = atomicAdd(&lc[rec[j].x >> 17], 1);
      srt[q] = make_uint2(rec[j].x & 0x1FFFFu, rec[j].y);
    }
  }
  __syncthreads();

#pragma unroll 1
  for (int i = wid * 16; i < wid * 16 + 16; ++i) {
    if (i >= nmax) break;
    const int s = lh[i];
    const int e2 = lh[i + 1];
    float a0 = 0.f, a1 = 0.f, a2 = 0.f, a3 = 0.f;
    float a4 = 0.f, a5 = 0.f, a6 = 0.f, a7 = 0.f;
#pragma unroll 1
    for (int p = s; p < e2; p += 16) {
      unsigned sx0, sx1, sx2, sx3;
      float w0, w1, w2, w3;
      {
        int i0 = p + 0 * 4 + g; bool k0 = i0 < e2; uint2 r = srt[k0 ? i0 : s];
        sx0 = r.x; w0 = k0 ? __uint_as_float(r.y) : 0.f;
      }
      {
        int i1 = p + 1 * 4 + g; bool k1 = i1 < e2; uint2 r = srt[k1 ? i1 : s];
        sx1 = r.x; w1 = k1 ? __uint_as_float(r.y) : 0.f;
      }
      {
        int i2 = p + 2 * 4 + g; bool k2 = i2 < e2; uint2 r = srt[k2 ? i2 : s];
        sx2 = r.x; w2 = k2 ? __uint_as_float(r.y) : 0.f;
      }
      {
        int i3 = p + 3 * 4 + g; bool k3 = i3 < e2; uint2 r = srt[k3 ? i3 : s];
        sx3 = r.x; w3 = k3 ? __uint_as_float(r.y) : 0.f;
      }
      uint4 v0 = *(const uint4*)(xw + (size_t)sx0 * DDIM + gcol);
      uint4 v1 = *(const uint4*)(xw + (size_t)sx1 * DDIM + gcol);
      uint4 v2 = *(const uint4*)(xw + (size_t)sx2 * DDIM + gcol);
      uint4 v3 = *(const uint4*)(xw + (size_t)sx3 * DDIM + gcol);
      a0 += w0 * bfLO(v0.x); a1 += w0 * bfHI(v0.x);
      a2 += w0 * bfLO(v0.y); a3 += w0 * bfHI(v0.y);
      a4 += w0 * bfLO(v0.z); a5 += w0 * bfHI(v0.z);
      a6 += w0 * bfLO(v0.w); a7 += w0 * bfHI(v0.w);
      a0 += w1 * bfLO(v1.x); a1 += w1 * bfHI(v1.x);
      a2 += w1 * bfLO(v1.y); a3 += w1 * bfHI(v1.y);
      a4 += w1 * bfLO(v1.z); a5 += w1 * bfHI(v1.z);
      a6 += w1 * bfLO(v1.w); a7 += w1 * bfHI(v1.w);
      a0 += w2 * bfLO(v2.x); a1 += w2 * bfHI(v2.x);
      a2 += w2 * bfLO(v2.y); a3 += w2 * bfHI(v2.y);
      a4 += w2 * bfLO(v2.z); a5 += w2 * bfHI(v2.z);
      a6 += w2 * bfLO(v2.w); a7 += w2 * bfHI(v2.w);
      a0 += w3 * bfLO(v3.x); a1 += w3 * bfHI(v3.x);
      a2 += w3 * bfLO(v3.y); a3 += w3 * bfHI(v3.y);
      a4 += w3 * bfLO(v3.z); a5 += w3 * bfHI(v3.z);
      a6 += w3 * bfLO(v3.w); a7 += w3 * bfHI(v3.w);
    }
    a0 += __shfl_xor(a0, 16); a0 += __shfl_xor(a0, 32);
    a1 += __shfl_xor(a1, 16); a1 += __shfl_xor(a1, 32);
    a2 += __shfl_xor(a2, 16); a2 += __shfl_xor(a2, 32);
    a3 += __shfl_xor(a3, 16); a3 += __shfl_xor(a3, 32);
    a4 += __shfl_xor(a4, 16); a4 += __shfl_xor(a4, 32);
    a5 += __shfl_xor(a5, 16); a5 += __shfl_xor(a5, 32);
    a6 += __shfl_xor(a6, 16); a6 += __shfl_xor(a6, 32);
    a7 += __shfl_xor(a7, 16); a7 += __shfl_xor(a7, 32);
    if (g < 2) {
      const float4 bv = *(const float4*)(bias + gcol + (g ? 4 : 0));
      float4 o = g ? make_float4(a4 + bv.x, a5 + bv.y, a6 + bv.z, a7 + bv.w)
                   : make_float4(a0 + bv.x, a1 + bv.y, a2 + bv.z, a3 + bv.w);
      *(float4*)(z + (size_t)(nbase + i) * DDIM + gcol + (g ? 4 : 0)) = o;
    }
  }
}

// ---------------- overflow fixup (normally empty) ----------------

__global__ __launch_bounds__(256) void k_ofl(const uint4* __restrict__ ofl,
                                             const int* __restrict__ oflcnt,
                                             const unsigned short* __restrict__ xw,
                                             float* __restrict__ z) {
  int n = oflcnt[0];
  if (n > OCAP) n = OCAP;
  for (int r = blockIdx.x; r < n; r += gridDim.x) {
    uint4 rec = ofl[r];
    float wgt = __uint_as_float(rec.z);
    int c = threadIdx.x;
    float v = bf16_to_f32(xw[(size_t)rec.y * DDIM + c]);
    atomicAdd(&z[(size_t)rec.x * DDIM + c], wgt * v);
  }
}

extern "C" void kernel_launch(void* const* d_in, const int* in_sizes, int n_in,
                              void* d_out, int out_size, void* d_ws, size_t ws_size,
                              hipStream_t stream) {
  const float* x = (const float*)d_in[0];
  const float* w = (const float*)d_in[1];
  const float* bias = (const float*)d_in[2];
  const int* esrc = (const int*)d_in[3];
  const int* edst = (const int*)d_in[4];
  const float* ew = (const float*)d_in[5];
  float* z = (float*)d_out;

  char* ws = (char*)d_ws;
  size_t off = 0;
  unsigned short* xw = (unsigned short*)(ws + off);
  off += (size_t)N_NODES * DDIM * 2;                        // 51.2 MB
  unsigned short* wt = (unsigned short*)(ws + off);
  off += (size_t)DDIM * DDIM * 2;                           // 128 KB
  int* bcur = (int*)(ws + off);
  off += (size_t)NB * 16 * 4;                               // 50 KB (line-padded cursors)
  int* oflcnt = (int*)(ws + off);
  off += 256;
  uint4* ofl = (uint4*)(ws + off);
  off += (size_t)OCAP * 16;                                 // 1 MB
  uint2* bin = (uint2*)(ws + off);
  off += (size_t)NB * CAP * 8;                              // 30 MB
  // total ~82.5 MB

  hipMemsetAsync(bcur, 0, (size_t)NB * 16 * 4 + 256, stream);  // bcur + oflcnt
  k_bin<<<(N_EDGES + BINBLK - 1) / BINBLK, 256, 0, stream>>>(esrc, edst, ew, bcur, bin,
                                                             ofl, oflcnt);
  k_cvtW<<<(DDIM * DDIM + 255) / 256, 256, 0, stream>>>(w, wt);
  k_gemm<<<(N_NODES + 127) / 128, 512, 0, stream>>>(x, wt, xw);
  dim3 ag(NB, 2);
  k_baggr<<<ag, 512, 0, stream>>>(bin, bcur, xw, bias, z);
  k_ofl<<<64, 256, 0, stream>>>(ofl, oflcnt, xw, z);
}